// Round 1
// 2180.055 us; speedup vs baseline: 1.0032x; 1.0032x over previous
//
#include <hip/hip_runtime.h>
#include <hip/hip_fp16.h>
#include <math.h>

typedef unsigned short u16;
typedef unsigned int u32;
typedef _Float16 half2_t __attribute__((ext_vector_type(2)));

#define B0N 8
#define LSEQ 9216
#define NSEQ 64
#define NCHUNK 288
#define DM 32
#define DPROJ 264
#define CONVCH 192
#define XCH 204  // fp16 xc row stride (even for half2; stride/2=102 words -> only 2-way bank alias)
#define URS 33   // ur row stride (f32)

#ifndef __has_builtin
#define __has_builtin(x) 0
#endif

__device__ __forceinline__ float silu_(float v) { return v / (1.f + __expf(-v)); }

__device__ __forceinline__ float fdot2_(half2_t a, half2_t b, float c) {
#if __has_builtin(__builtin_amdgcn_fdot2)
  return __builtin_amdgcn_fdot2(a, b, c, false);
#else
  return c + (float)a.x * (float)b.x + (float)a.y * (float)b.y;
#endif
}

// ---------------- K1: LayerNorm(256) + split -> u (64,9216,32) fp16 ----------------
__global__ __launch_bounds__(256) void k1_ln_split(const float* __restrict__ x,
                                                   const float* __restrict__ lnw,
                                                   const float* __restrict__ lnb,
                                                   __half* __restrict__ u) {
  __shared__ float tile[256 * 33];  // [c][ll]
  __shared__ float mu[32], rs[32], wv[256], bv[256];
  const int b = blockIdx.y, l0 = blockIdx.x * 32, t = threadIdx.x;
  wv[t] = lnw[t];
  bv[t] = lnb[t];
#pragma unroll 4
  for (int i = 0; i < 32; ++i) {
    int c = i * 8 + (t >> 5), ll = t & 31;
    tile[c * 33 + ll] = x[((size_t)b * 256 + c) * LSEQ + l0 + ll];
  }
  __syncthreads();
  if (t < 32) {
    float s = 0.f, s2 = 0.f;
    for (int c = 0; c < 256; ++c) {
      float v = tile[c * 33 + t];
      s += v; s2 += v * v;
    }
    float m = s * (1.f / 256.f);
    mu[t] = m;
    rs[t] = rsqrtf(s2 * (1.f / 256.f) - m * m + 1e-5f);
  }
  __syncthreads();
#pragma unroll 4
  for (int i = 0; i < 32; ++i) {
    int sp = i >> 2, sub = i & 3;
    int ll = sub * 8 + (t >> 5), dm = t & 31;
    int c = sp * 32 + dm;
    float v = (tile[c * 33 + ll] - mu[ll]) * rs[ll] * wv[c] + bv[c];
    u[(((size_t)(sp * B0N + b)) * LSEQ + l0 + ll) * DM + dm] = __float2half(v);
  }
}

// ---------------- K2: in-proj + conv + dt + per-chunk states ----------------
// If xcg != nullptr, also exports:
//   xcg  [sq*NCHUNK+c][32][192] fp16  (post conv+silu channels 0..191)
//   dtvg/acsg [sq*NCHUNK+c][h*32+l] f32
__global__ __launch_bounds__(256) void k2_states(
    const __half* __restrict__ u, const float* __restrict__ Win,
    const float* __restrict__ convw, const float* __restrict__ convb,
    const float* __restrict__ dtbias, const float* __restrict__ Alog,
    __half* __restrict__ S, float* __restrict__ cdec,
    __half* __restrict__ xcg, float* __restrict__ dtvg, float* __restrict__ acsg) {
  __shared__ float ur[34 * URS];
  __shared__ __align__(16) float WlH[32 * 40];
  __shared__ __align__(16) float CH[34 * 40];
  __shared__ __align__(16) __half xch[32 * XCH];
  __shared__ float dtraw_s[256];
  __shared__ float dtv[256], acs[256], wv2[256];
  const int c = blockIdx.x, sq = blockIdx.y, t = threadIdx.x;
  const int l0 = c * 32;
  const size_t ubase = (size_t)sq * (LSEQ * DM);
  for (int idx = t; idx < 34 * 32; idx += 256) {
    int r = idx >> 5, dm = idx & 31;
    int l = l0 - 2 + r;
    ur[r * URS + dm] = (l >= 0) ? __half2float(u[ubase + (size_t)l * DM + dm]) : 0.f;
  }
  __syncthreads();
  for (int q = 0; q < 5; ++q) {
    for (int idx = t; idx < 1280; idx += 256) {
      int dm = idx / 40, j = idx % 40;
      WlH[idx] = Win[dm * DPROJ + 64 + q * 40 + j];
    }
    __syncthreads();
    for (int q4 = t; q4 < 340; q4 += 256) {
      int r = q4 / 10, jq = q4 % 10;
      float a0 = 0, a1 = 0, a2 = 0, a3 = 0;
#pragma unroll
      for (int dm = 0; dm < 32; ++dm) {
        float uu = ur[r * URS + dm];
        const float4 w = *(const float4*)&WlH[dm * 40 + jq * 4];
        a0 += uu * w.x; a1 += uu * w.y; a2 += uu * w.z; a3 += uu * w.w;
      }
      *(float4*)&CH[r * 40 + jq * 4] = make_float4(a0, a1, a2, a3);
    }
    __syncthreads();
    for (int idx = t; idx < 1280; idx += 256) {
      int l = idx / 40, jj = idx % 40;
      int ch = q * 40 + jj;
      if (ch < CONVCH) {
        float v = CH[l * 40 + jj] * convw[ch * 3 + 0] +
                  CH[(l + 1) * 40 + jj] * convw[ch * 3 + 1] +
                  CH[(l + 2) * 40 + jj] * convw[ch * 3 + 2] + convb[ch];
        xch[l * XCH + ch] = __float2half(silu_(v));
      } else {
        dtraw_s[l * 8 + (ch - 192)] = CH[(l + 2) * 40 + jj];
      }
    }
    __syncthreads();
  }
  if (t < 8) {
    float A = -__expf(Alog[t]);
    float bias = dtbias[t];
    float ac = 0.f;
    for (int l = 0; l < 32; ++l) {
      float raw = dtraw_s[l * 8 + t] + bias;
      float dt = (raw > 20.f) ? raw : log1pf(__expf(raw));
      dtv[t * 32 + l] = dt;
      ac += dt * A;
      acs[t * 32 + l] = ac;
    }
    cdec[(sq * NCHUNK + c) * 8 + t] = __expf(ac);
  }
  __syncthreads();
  {
    int h = t >> 5;
    wv2[t] = __expf(acs[h * 32 + 31] - acs[t]) * dtv[t];
  }
  // export xc / dtv / acs for k4_out_fast (independent of wv2/states; overlaps)
  if (xcg) {
    const size_t xbase = (size_t)(sq * NCHUNK + c) * (32 * 192);
    uint2* xg = (uint2*)(xcg + xbase);
    for (int idx = t; idx < 1536; idx += 256) {
      int l = idx / 48, j = idx % 48;  // 48 x 8B per 192-half row
      xg[idx] = *(const uint2*)&xch[l * XCH + j * 4];
    }
    const size_t dbase = (size_t)(sq * NCHUNK + c) * 256;
    dtvg[dbase + t] = dtv[t];
    acsg[dbase + t] = acs[t];
  }
  __syncthreads();
  // S[h][p][n] = sum_l wv2[h][l]*x[l][h8+p] * B[l][n]
  const size_t sbase = (size_t)(sq * NCHUNK + c) * 4096;
  const int hp2 = t >> 2, h2 = hp2 >> 3, p2 = hp2 & 7, n0 = (t & 3) << 4;
  float xw[32];
#pragma unroll
  for (int l = 0; l < 32; ++l)
    xw[l] = wv2[h2 * 32 + l] * (float)xch[l * XCH + h2 * 8 + p2];
  const size_t sb2 = sbase + hp2 * 64;
  for (int j = 0; j < 16; j += 2) {
    int n = n0 + j;
    float a0 = 0.f, a1 = 0.f;
#pragma unroll
    for (int l = 0; l < 32; ++l) {
      half2_t b2 = *(const half2_t*)&xch[l * XCH + 64 + n];
      a0 += xw[l] * (float)b2.x;
      a1 += xw[l] * (float)b2.y;
    }
    half2_t r;
    r.x = (_Float16)a0;
    r.y = (_Float16)a1;
    *(half2_t*)&S[sb2 + n] = r;
  }
}

// ---------------- K3: in-place exclusive scan over chunks ----------------
__global__ __launch_bounds__(512) void k3_scan(__half* __restrict__ S,
                                               const float* __restrict__ cdec) {
  const int sq = blockIdx.x >> 3, h = blockIdx.x & 7, t = threadIdx.x;
  float carry = 0.f;
  for (int c = 0; c < NCHUNK; ++c) {
    size_t idx = (size_t)(sq * NCHUNK + c) * 4096 + h * 512 + t;
    float s = __half2float(S[idx]);
    S[idx] = __float2half(carry);
    carry = carry * cdec[(sq * NCHUNK + c) * 8 + h] + s;
  }
}

// ---------------- K4 (fast): output pass, loads xc/dtv/acs instead of recomputing ----------------
__global__ __launch_bounds__(256) void k4_out_fast(
    const __half* __restrict__ u, const float* __restrict__ Win,
    const float* __restrict__ Dp, const float* __restrict__ rmsw,
    const float* __restrict__ Wout, const float* __restrict__ skip,
    const __half* __restrict__ S, const __half* __restrict__ xcg,
    const float* __restrict__ dtvg, const float* __restrict__ acsg,
    __half* __restrict__ ym) {
  __shared__ float ur[34 * URS];                  // rows 2..33 used (z recompute)
  __shared__ __align__(16) __half pv[64 * 66];    // 8448 B
  __shared__ __align__(16) __half xch[32 * XCH];  // 13056 B
  __shared__ float dtv[256], acs[256];
  __shared__ float G[32 * 33];
  __shared__ __half ybuf[32 * 66];
  __shared__ float scl[32];
  const int c = blockIdx.x, sq = blockIdx.y, t = threadIdx.x;
  const int l0 = c * 32;
  const size_t ubase = (size_t)sq * (LSEQ * DM);
  // ur rows 2..33 (only rows needed by the z-gate)
  for (int idx = t; idx < 1024; idx += 256) {
    int r = idx >> 5, dm = idx & 31;
    ur[(r + 2) * URS + dm] = __half2float(u[ubase + (size_t)(l0 + r) * DM + dm]);
  }
  // xc tile: 32x192 fp16, contiguous in global; 16B global loads, 8B LDS stores
  {
    const size_t xbase = (size_t)(sq * NCHUNK + c) * (32 * 192);
    const uint4* xg = (const uint4*)(xcg + xbase);
    for (int idx = t; idx < 768; idx += 256) {
      int l = idx / 24, j = idx % 24;
      uint4 v = xg[idx];
      uint2* d = (uint2*)&xch[l * XCH + j * 8];
      d[0] = make_uint2(v.x, v.y);
      d[1] = make_uint2(v.z, v.w);
    }
  }
  {
    const size_t dbase = (size_t)(sq * NCHUNK + c) * 256;
    dtv[t] = dtvg[dbase + t];
    acs[t] = acsg[dbase + t];
  }
  // prev-state load into LDS, natural S layout [hp][n] (+pad)
  const size_t sbase = (size_t)(sq * NCHUNK + c) * 4096;
#pragma unroll
  for (int i = 0; i < 16; ++i) {
    int idx = i * 256 + t;
    int hp = idx >> 6, n = idx & 63;
    pv[hp * 66 + n] = S[sbase + idx];
  }
  __syncthreads();
  // G[l][s2] = sum_n C[l][n]*B[s2][n]  (fdot2 over contiguous n)
  for (int idx = t; idx < 1024; idx += 256) {
    int l = idx >> 5, s2 = idx & 31;
    const half2_t* Crow = (const half2_t*)&xch[l * XCH + 128];
    const half2_t* Brow = (const half2_t*)&xch[s2 * XCH + 64];
    float acc = 0.f;
#pragma unroll
    for (int j = 0; j < 32; ++j) acc = fdot2_(Crow[j], Brow[j], acc);
    G[l * 33 + s2] = acc;
  }
  __syncthreads();
  // Yd + Yoff: thread = (row lY, head h), 8 p-outputs in registers
  {
    const int lY = t & 31, h = t >> 5;
    const float al = acs[h * 32 + lY];
    float accd[8] = {0, 0, 0, 0, 0, 0, 0, 0};
    for (int s2 = 0; s2 <= lY; ++s2) {
      float coef = G[lY * 33 + s2] * __expf(al - acs[h * 32 + s2]) * dtv[h * 32 + s2];
      const half2_t* xp = (const half2_t*)&xch[s2 * XCH + h * 8];
#pragma unroll
      for (int j = 0; j < 4; ++j) {
        half2_t v = xp[j];
        accd[2 * j] += coef * (float)v.x;
        accd[2 * j + 1] += coef * (float)v.y;
      }
    }
    float acco[8] = {0, 0, 0, 0, 0, 0, 0, 0};
    const half2_t* Crow = (const half2_t*)&xch[lY * XCH + 128];
    for (int i = 0; i < 32; ++i) {
      half2_t c2 = Crow[i];
#pragma unroll
      for (int p = 0; p < 8; ++p) {
        half2_t pvv = *(const half2_t*)&pv[(h * 8 + p) * 66 + 2 * i];
        acco[p] = fdot2_(c2, pvv, acco[p]);
      }
    }
    const float eacl = __expf(acs[t]);  // t == h*32+lY
#pragma unroll
    for (int p = 0; p < 8; ++p)
      ybuf[lY * 66 + h * 8 + p] = __float2half(accd[p] + acco[p] * eacl);
  }
  __syncthreads();
  // +D*xs, gate with silu(z); z recomputed from u with register-cached Win column
  {
    const int hp = t & 63;
    float wz[32];
#pragma unroll
    for (int dm = 0; dm < 32; ++dm) wz[dm] = Win[dm * DPROJ + hp];
    const float dcoef = Dp[hp >> 3];
#pragma unroll
    for (int k = 0; k < 8; ++k) {
      int l = (k * 256 + t) >> 6;
      float z = 0.f;
#pragma unroll
      for (int dm = 0; dm < 32; ++dm) z += ur[(l + 2) * URS + dm] * wz[dm];
      float y = __half2float(ybuf[l * 66 + hp]) + (float)xch[l * XCH + hp] * dcoef;
      y *= z / (1.f + __expf(-z));
      ybuf[l * 66 + hp] = __float2half(y);
    }
  }
  __syncthreads();
  if (t < 32) {
    float s2s = 0.f;
#pragma unroll 16
    for (int hp = 0; hp < 64; ++hp) {
      float v = __half2float(ybuf[t * 66 + hp]);
      s2s += v * v;
    }
    scl[t] = rsqrtf(s2s * (1.f / 64.f) + 1e-5f);
  }
  __syncthreads();
  for (int idx = t; idx < 2048; idx += 256) {
    int l = idx >> 6, hp = idx & 63;
    ybuf[l * 66 + hp] = __float2half(__half2float(ybuf[l * 66 + hp]) * scl[l] * rmsw[hp]);
  }
  __syncthreads();
  const float skipv = skip[0];
#pragma unroll
  for (int i = 0; i < 4; ++i) {
    int dm = t & 31, l = (t >> 5) + i * 8;
    float acc = 0.f;
#pragma unroll 16
    for (int hp = 0; hp < 64; ++hp)
      acc += __half2float(ybuf[l * 66 + hp]) * Wout[hp * 32 + dm];
    size_t g = ubase + (size_t)(l0 + l) * DM + dm;
    ym[g] = __float2half(acc + skipv * __half2float(u[g]));
  }
}

// ---------------- K4 (fallback): output pass with in-proj recompute ----------------
__global__ __launch_bounds__(256) void k4_out(
    const __half* __restrict__ u, const float* __restrict__ Win,
    const float* __restrict__ convw, const float* __restrict__ convb,
    const float* __restrict__ dtbias, const float* __restrict__ Alog,
    const float* __restrict__ Dp, const float* __restrict__ rmsw,
    const float* __restrict__ Wout, const float* __restrict__ skip,
    const __half* __restrict__ S, __half* __restrict__ ym) {
  __shared__ float ur[34 * URS];                 // 4488 B
  __shared__ __align__(16) float scratch[2640];  // 10560 B: WlH(1280)+CH(1360); later pv fp16 [64][66]
  __shared__ __align__(16) __half xch[32 * XCH]; // 13056 B
  __shared__ float dtraw_eac[256];               // dtraw [l][h] first, then eac[h][l]
  __shared__ float dtv[256], acs[256];
  __shared__ float G[32 * 33];                   // 4224 B
  __shared__ __half ybuf[32 * 66];               // 4224 B
  __shared__ float scl[32];
  float* WlH = scratch;
  float* CH = scratch + 1280;
  __half* pv = (__half*)scratch;  // [hp][66] fp16, overlays after GEMM phase
  const int c = blockIdx.x, sq = blockIdx.y, t = threadIdx.x;
  const int l0 = c * 32;
  const size_t ubase = (size_t)sq * (LSEQ * DM);
  for (int idx = t; idx < 34 * 32; idx += 256) {
    int r = idx >> 5, dm = idx & 31;
    int l = l0 - 2 + r;
    ur[r * URS + dm] = (l >= 0) ? __half2float(u[ubase + (size_t)l * DM + dm]) : 0.f;
  }
  __syncthreads();
  for (int q = 0; q < 5; ++q) {
    for (int idx = t; idx < 1280; idx += 256) {
      int dm = idx / 40, j = idx % 40;
      WlH[idx] = Win[dm * DPROJ + 64 + q * 40 + j];
    }
    __syncthreads();
    for (int q4 = t; q4 < 340; q4 += 256) {
      int r = q4 / 10, jq = q4 % 10;
      float a0 = 0, a1 = 0, a2 = 0, a3 = 0;
#pragma unroll
      for (int dm = 0; dm < 32; ++dm) {
        float uu = ur[r * URS + dm];
        const float4 w = *(const float4*)&WlH[dm * 40 + jq * 4];
        a0 += uu * w.x; a1 += uu * w.y; a2 += uu * w.z; a3 += uu * w.w;
      }
      *(float4*)&CH[r * 40 + jq * 4] = make_float4(a0, a1, a2, a3);
    }
    __syncthreads();
    for (int idx = t; idx < 1280; idx += 256) {
      int l = idx / 40, jj = idx % 40;
      int ch = q * 40 + jj;
      if (ch < CONVCH) {
        float v = CH[l * 40 + jj] * convw[ch * 3 + 0] +
                  CH[(l + 1) * 40 + jj] * convw[ch * 3 + 1] +
                  CH[(l + 2) * 40 + jj] * convw[ch * 3 + 2] + convb[ch];
        xch[l * XCH + ch] = __float2half(silu_(v));
      } else {
        dtraw_eac[l * 8 + (ch - 192)] = CH[(l + 2) * 40 + jj];
      }
    }
    __syncthreads();
  }
  if (t < 8) {
    float A = -__expf(Alog[t]);
    float bias = dtbias[t];
    float ac = 0.f;
    for (int l = 0; l < 32; ++l) {
      float raw = dtraw_eac[l * 8 + t] + bias;
      float dt = (raw > 20.f) ? raw : log1pf(__expf(raw));
      dtv[t * 32 + l] = dt;
      ac += dt * A;
      acs[t * 32 + l] = ac;
    }
  }
  __syncthreads();
  dtraw_eac[t] = __expf(acs[t]);  // eac[h*32+l]; each thread reads back only its own slot
  float* eac = dtraw_eac;
  // prev-state load into LDS, natural S layout [hp][n] (+pad)
  const size_t sbase = (size_t)(sq * NCHUNK + c) * 4096;
#pragma unroll
  for (int i = 0; i < 16; ++i) {
    int idx = i * 256 + t;
    int hp = idx >> 6, n = idx & 63;
    pv[hp * 66 + n] = S[sbase + idx];
  }
  // G[l][s2] = sum_n C[l][n]*B[s2][n]  (fdot2 over contiguous n)
  for (int idx = t; idx < 1024; idx += 256) {
    int l = idx >> 5, s2 = idx & 31;
    const half2_t* Crow = (const half2_t*)&xch[l * XCH + 128];
    const half2_t* Brow = (const half2_t*)&xch[s2 * XCH + 64];
    float acc = 0.f;
#pragma unroll
    for (int j = 0; j < 32; ++j) acc = fdot2_(Crow[j], Brow[j], acc);
    G[l * 33 + s2] = acc;
  }
  __syncthreads();
  // Yd + Yoff: thread = (row lY, head h), 8 p-outputs in registers
  {
    const int lY = t & 31, h = t >> 5;
    const float al = acs[h * 32 + lY];
    float accd[8] = {0, 0, 0, 0, 0, 0, 0, 0};
    for (int s2 = 0; s2 <= lY; ++s2) {
      float coef = G[lY * 33 + s2] * __expf(al - acs[h * 32 + s2]) * dtv[h * 32 + s2];
      const half2_t* xp = (const half2_t*)&xch[s2 * XCH + h * 8];
#pragma unroll
      for (int j = 0; j < 4; ++j) {
        half2_t v = xp[j];
        accd[2 * j] += coef * (float)v.x;
        accd[2 * j + 1] += coef * (float)v.y;
      }
    }
    float acco[8] = {0, 0, 0, 0, 0, 0, 0, 0};
    const half2_t* Crow = (const half2_t*)&xch[lY * XCH + 128];
    for (int i = 0; i < 32; ++i) {
      half2_t c2 = Crow[i];
#pragma unroll
      for (int p = 0; p < 8; ++p) {
        half2_t pvv = *(const half2_t*)&pv[(h * 8 + p) * 66 + 2 * i];
        acco[p] = fdot2_(c2, pvv, acco[p]);
      }
    }
    const float eacl = eac[h * 32 + lY];
#pragma unroll
    for (int p = 0; p < 8; ++p)
      ybuf[lY * 66 + h * 8 + p] = __float2half(accd[p] + acco[p] * eacl);
  }
  __syncthreads();
  // +D*xs, gate with silu(z); z recomputed from u with register-cached Win column
  {
    const int hp = t & 63;
    float wz[32];
#pragma unroll
    for (int dm = 0; dm < 32; ++dm) wz[dm] = Win[dm * DPROJ + hp];
    const float dcoef = Dp[hp >> 3];
#pragma unroll
    for (int k = 0; k < 8; ++k) {
      int l = (k * 256 + t) >> 6;
      float z = 0.f;
#pragma unroll
      for (int dm = 0; dm < 32; ++dm) z += ur[(l + 2) * URS + dm] * wz[dm];
      float y = __half2float(ybuf[l * 66 + hp]) + (float)xch[l * XCH + hp] * dcoef;
      y *= z / (1.f + __expf(-z));
      ybuf[l * 66 + hp] = __float2half(y);
    }
  }
  __syncthreads();
  if (t < 32) {
    float s2s = 0.f;
#pragma unroll 16
    for (int hp = 0; hp < 64; ++hp) {
      float v = __half2float(ybuf[t * 66 + hp]);
      s2s += v * v;
    }
    scl[t] = rsqrtf(s2s * (1.f / 64.f) + 1e-5f);
  }
  __syncthreads();
  for (int idx = t; idx < 2048; idx += 256) {
    int l = idx >> 6, hp = idx & 63;
    ybuf[l * 66 + hp] = __float2half(__half2float(ybuf[l * 66 + hp]) * scl[l] * rmsw[hp]);
  }
  __syncthreads();
  const float skipv = skip[0];
#pragma unroll
  for (int i = 0; i < 4; ++i) {
    int dm = t & 31, l = (t >> 5) + i * 8;
    float acc = 0.f;
#pragma unroll 16
    for (int hp = 0; hp < 64; ++hp)
      acc += __half2float(ybuf[l * 66 + hp]) * Wout[hp * 32 + dm];
    size_t g = ubase + (size_t)(l0 + l) * DM + dm;
    ym[g] = __float2half(acc + skipv * __half2float(u[g]));
  }
}

// ---------------- K5: regroup + LN2 + proj(256x256) + bias + transpose ----------------
__global__ __launch_bounds__(256) void k5_ln_proj(const __half* __restrict__ ym,
                                                  const float* __restrict__ lnw,
                                                  const float* __restrict__ lnb,
                                                  const float* __restrict__ pw,
                                                  const float* __restrict__ pb,
                                                  float* __restrict__ outp) {
  __shared__ float yf[8448];  // LN phase: [32][257]; epilogue: res [256][33]
  __shared__ float mu[32], rs[32], wv[256], bv[256];
  const int b = blockIdx.y, l0 = blockIdx.x * 32, t = threadIdx.x;
  wv[t] = lnw[t];
  bv[t] = lnb[t];
  for (int sp = 0; sp < 8; ++sp) {
#pragma unroll
    for (int i = 0; i < 4; ++i) {
      int idx = i * 256 + t;
      int ll = idx >> 5, dm = idx & 31;
      yf[ll * 257 + sp * 32 + dm] =
          __half2float(ym[(((size_t)(sp * B0N + b)) * LSEQ + l0 + ll) * DM + dm]);
    }
  }
  __syncthreads();
  if (t < 32) {
    float s = 0.f, s2 = 0.f;
    for (int ch = 0; ch < 256; ++ch) {
      float v = yf[t * 257 + ch];
      s += v; s2 += v * v;
    }
    float m = s * (1.f / 256.f);
    mu[t] = m;
    rs[t] = rsqrtf(s2 * (1.f / 256.f) - m * m + 1e-5f);
  }
  __syncthreads();
#pragma unroll 8
  for (int i = 0; i < 32; ++i) {
    int idx = i * 256 + t;
    int ll = idx >> 8, ch = idx & 255;
    yf[ll * 257 + ch] = (yf[ll * 257 + ch] - mu[ll]) * rs[ll] * wv[ch] + bv[ch];
  }
  __syncthreads();
  const int llg = t >> 5, og = t & 31;
  float acc[4][8];
#pragma unroll
  for (int k = 0; k < 4; ++k)
#pragma unroll
    for (int j = 0; j < 8; ++j) acc[k][j] = 0.f;
  for (int ch = 0; ch < 256; ++ch) {
    const float4 w0 = *(const float4*)(pw + (size_t)ch * 256 + og * 8);
    const float4 w1 = *(const float4*)(pw + (size_t)ch * 256 + og * 8 + 4);
#pragma unroll
    for (int k = 0; k < 4; ++k) {
      float y = yf[(llg * 4 + k) * 257 + ch];
      acc[k][0] += y * w0.x; acc[k][1] += y * w0.y; acc[k][2] += y * w0.z; acc[k][3] += y * w0.w;
      acc[k][4] += y * w1.x; acc[k][5] += y * w1.y; acc[k][6] += y * w1.z; acc[k][7] += y * w1.w;
    }
  }
  __syncthreads();  // all yf reads done before overlay
  float* res = yf;  // [256][33]
#pragma unroll
  for (int j = 0; j < 8; ++j) {
    float bias = pb[og * 8 + j];
#pragma unroll
    for (int k = 0; k < 4; ++k)
      res[(og * 8 + j) * 33 + llg * 4 + k] = acc[k][j] + bias;
  }
  __syncthreads();
  for (int idx = t; idx < 8192; idx += 256) {
    int o = idx >> 5, l = idx & 31;
    outp[((size_t)(b * 256 + o)) * LSEQ + l0 + l] = res[o * 33 + l];
  }
}

extern "C" void kernel_launch(void* const* d_in, const int* in_sizes, int n_in,
                              void* d_out, int out_size, void* d_ws, size_t ws_size,
                              hipStream_t stream) {
  (void)in_sizes; (void)n_in; (void)out_size;
  const float* x     = (const float*)d_in[0];
  const float* lnw   = (const float*)d_in[1];
  const float* lnb   = (const float*)d_in[2];
  const float* skip  = (const float*)d_in[3];
  const float* pw    = (const float*)d_in[4];
  const float* pb    = (const float*)d_in[5];
  const float* Win   = (const float*)d_in[6];
  const float* convw = (const float*)d_in[7];
  const float* convb = (const float*)d_in[8];
  const float* dtb   = (const float*)d_in[9];
  const float* Alog  = (const float*)d_in[10];
  const float* Dp    = (const float*)d_in[11];
  const float* rmsw  = (const float*)d_in[12];
  const float* Wout  = (const float*)d_in[13];
  float* outp = (float*)d_out;

  // workspace layout (fp16 tensors):
  //   base (always): u 37,748,736 | S 150,994,944 | cdec 589,824 | ym 37,748,736 = 227,082,240
  //   fast-path extension: xc 226,492,416 | dtv 18,874,368 | acs 18,874,368 -> NEED_BIG 491,323,392
  const size_t NEED = 227082240ull;
  const size_t XCB  = (size_t)NSEQ * NCHUNK * (32 * 192) * 2;  // 226,492,416
  const size_t DTB  = (size_t)NSEQ * NCHUNK * 256 * 4;         //  18,874,368
  const size_t NEED_BIG = NEED + XCB + 2 * DTB;                // 491,323,392
  if (ws_size < NEED) return;
  char* ws = (char*)d_ws;
  __half* u    = (__half*)ws;                    //  37,748,736 B
  __half* S    = (__half*)(ws + 37748736);       // 150,994,944 B
  float*  cdec = (float*)(ws + 188743680);       //     589,824 B
  __half* ym   = (__half*)(ws + 189333504);      //  37,748,736 B
  __half* xcg = nullptr;
  float*  dtvg = nullptr;
  float*  acsg = nullptr;
  if (ws_size >= NEED_BIG) {
    xcg  = (__half*)(ws + NEED);
    dtvg = (float*)(ws + NEED + XCB);
    acsg = (float*)(ws + NEED + XCB + DTB);
  }

  k1_ln_split<<<dim3(288, 8), 256, 0, stream>>>(x, lnw, lnb, u);
  k2_states<<<dim3(288, 64), 256, 0, stream>>>(u, Win, convw, convb, dtb, Alog, S, cdec,
                                               xcg, dtvg, acsg);
  k3_scan<<<dim3(512), 512, 0, stream>>>(S, cdec);
  if (xcg) {
    k4_out_fast<<<dim3(288, 64), 256, 0, stream>>>(u, Win, Dp, rmsw, Wout, skip, S,
                                                   xcg, dtvg, acsg, ym);
  } else {
    k4_out<<<dim3(288, 64), 256, 0, stream>>>(u, Win, convw, convb, dtb, Alog, Dp, rmsw,
                                              Wout, skip, S, ym);
  }
  k5_ln_proj<<<dim3(288, 8), 256, 0, stream>>>(ym, lnw, lnb, pw, pb, outp);
}

// Round 2
// 1731.575 us; speedup vs baseline: 1.2630x; 1.2590x over previous
//
#include <hip/hip_runtime.h>
#include <hip/hip_fp16.h>
#include <math.h>

typedef unsigned short u16;
typedef unsigned int u32;
typedef _Float16 half2_t __attribute__((ext_vector_type(2)));
typedef _Float16 f16x8 __attribute__((ext_vector_type(8)));
typedef float f32x4 __attribute__((ext_vector_type(4)));

#define B0N 8
#define LSEQ 9216
#define NSEQ 64
#define NCHUNK 288
#define DM 32
#define DPROJ 264
#define CONVCH 192
#define XCH 204   // k2 xc row stride (fp16)
#define XC4 208   // k4 xc row stride (fp16, 416B rows -> 16B-aligned for ds_read_b128)
#define URS 33    // k2 ur row stride (f32)
#define URH 40    // k4 ur row stride (fp16, 80B rows -> 16B-aligned, 2-way banks)
#define CHS 193   // k4 CH row stride (f32)
#define ZBS 66    // k4 zbuf row stride (fp16)

#ifndef __has_builtin
#define __has_builtin(x) 0
#endif

__device__ __forceinline__ float silu_(float v) { return v / (1.f + __expf(-v)); }

__device__ __forceinline__ float fdot2_(half2_t a, half2_t b, float c) {
#if __has_builtin(__builtin_amdgcn_fdot2)
  return __builtin_amdgcn_fdot2(a, b, c, false);
#else
  return c + (float)a.x * (float)b.x + (float)a.y * (float)b.y;
#endif
}

// ---------------- K1: LayerNorm(256) + split -> u (64,9216,32) fp16 ----------------
__global__ __launch_bounds__(256) void k1_ln_split(const float* __restrict__ x,
                                                   const float* __restrict__ lnw,
                                                   const float* __restrict__ lnb,
                                                   __half* __restrict__ u) {
  __shared__ float tile[256 * 33];  // [c][ll]
  __shared__ float mu[32], rs[32], wv[256], bv[256];
  const int b = blockIdx.y, l0 = blockIdx.x * 32, t = threadIdx.x;
  wv[t] = lnw[t];
  bv[t] = lnb[t];
#pragma unroll 4
  for (int i = 0; i < 32; ++i) {
    int c = i * 8 + (t >> 5), ll = t & 31;
    tile[c * 33 + ll] = x[((size_t)b * 256 + c) * LSEQ + l0 + ll];
  }
  __syncthreads();
  if (t < 32) {
    float s = 0.f, s2 = 0.f;
    for (int c = 0; c < 256; ++c) {
      float v = tile[c * 33 + t];
      s += v; s2 += v * v;
    }
    float m = s * (1.f / 256.f);
    mu[t] = m;
    rs[t] = rsqrtf(s2 * (1.f / 256.f) - m * m + 1e-5f);
  }
  __syncthreads();
#pragma unroll 4
  for (int i = 0; i < 32; ++i) {
    int sp = i >> 2, sub = i & 3;
    int ll = sub * 8 + (t >> 5), dm = t & 31;
    int c = sp * 32 + dm;
    float v = (tile[c * 33 + ll] - mu[ll]) * rs[ll] * wv[c] + bv[c];
    u[(((size_t)(sp * B0N + b)) * LSEQ + l0 + ll) * DM + dm] = __float2half(v);
  }
}

// ---------------- K2: in-proj + conv + dt + per-chunk states ----------------
__global__ __launch_bounds__(256) void k2_states(
    const __half* __restrict__ u, const float* __restrict__ Win,
    const float* __restrict__ convw, const float* __restrict__ convb,
    const float* __restrict__ dtbias, const float* __restrict__ Alog,
    __half* __restrict__ S, float* __restrict__ cdec) {
  __shared__ float ur[34 * URS];
  __shared__ __align__(16) float WlH[32 * 40];
  __shared__ __align__(16) float CH[34 * 40];
  __shared__ __align__(16) __half xch[32 * XCH];
  __shared__ float dtraw_s[256];
  __shared__ float dtv[256], acs[256], wv2[256];
  const int c = blockIdx.x, sq = blockIdx.y, t = threadIdx.x;
  const int l0 = c * 32;
  const size_t ubase = (size_t)sq * (LSEQ * DM);
  for (int idx = t; idx < 34 * 32; idx += 256) {
    int r = idx >> 5, dm = idx & 31;
    int l = l0 - 2 + r;
    ur[r * URS + dm] = (l >= 0) ? __half2float(u[ubase + (size_t)l * DM + dm]) : 0.f;
  }
  __syncthreads();
  for (int q = 0; q < 5; ++q) {
    for (int idx = t; idx < 1280; idx += 256) {
      int dm = idx / 40, j = idx % 40;
      WlH[idx] = Win[dm * DPROJ + 64 + q * 40 + j];
    }
    __syncthreads();
    for (int q4 = t; q4 < 340; q4 += 256) {
      int r = q4 / 10, jq = q4 % 10;
      float a0 = 0, a1 = 0, a2 = 0, a3 = 0;
#pragma unroll
      for (int dm = 0; dm < 32; ++dm) {
        float uu = ur[r * URS + dm];
        const float4 w = *(const float4*)&WlH[dm * 40 + jq * 4];
        a0 += uu * w.x; a1 += uu * w.y; a2 += uu * w.z; a3 += uu * w.w;
      }
      *(float4*)&CH[r * 40 + jq * 4] = make_float4(a0, a1, a2, a3);
    }
    __syncthreads();
    for (int idx = t; idx < 1280; idx += 256) {
      int l = idx / 40, jj = idx % 40;
      int ch = q * 40 + jj;
      if (ch < CONVCH) {
        float v = CH[l * 40 + jj] * convw[ch * 3 + 0] +
                  CH[(l + 1) * 40 + jj] * convw[ch * 3 + 1] +
                  CH[(l + 2) * 40 + jj] * convw[ch * 3 + 2] + convb[ch];
        xch[l * XCH + ch] = __float2half(silu_(v));
      } else {
        dtraw_s[l * 8 + (ch - 192)] = CH[(l + 2) * 40 + jj];
      }
    }
    __syncthreads();
  }
  if (t < 8) {
    float A = -__expf(Alog[t]);
    float bias = dtbias[t];
    float ac = 0.f;
    for (int l = 0; l < 32; ++l) {
      float raw = dtraw_s[l * 8 + t] + bias;
      float dt = (raw > 20.f) ? raw : log1pf(__expf(raw));
      dtv[t * 32 + l] = dt;
      ac += dt * A;
      acs[t * 32 + l] = ac;
    }
    cdec[(sq * NCHUNK + c) * 8 + t] = __expf(ac);
  }
  __syncthreads();
  {
    int h = t >> 5;
    wv2[t] = __expf(acs[h * 32 + 31] - acs[t]) * dtv[t];
  }
  __syncthreads();
  // S[h][p][n] = sum_l wv2[h][l]*x[l][h8+p] * B[l][n]
  const size_t sbase = (size_t)(sq * NCHUNK + c) * 4096;
  const int hp2 = t >> 2, h2 = hp2 >> 3, p2 = hp2 & 7, n0 = (t & 3) << 4;
  float xw[32];
#pragma unroll
  for (int l = 0; l < 32; ++l)
    xw[l] = wv2[h2 * 32 + l] * (float)xch[l * XCH + h2 * 8 + p2];
  const size_t sb2 = sbase + hp2 * 64;
  for (int j = 0; j < 16; j += 2) {
    int n = n0 + j;
    float a0 = 0.f, a1 = 0.f;
#pragma unroll
    for (int l = 0; l < 32; ++l) {
      half2_t b2 = *(const half2_t*)&xch[l * XCH + 64 + n];
      a0 += xw[l] * (float)b2.x;
      a1 += xw[l] * (float)b2.y;
    }
    half2_t r;
    r.x = (_Float16)a0;
    r.y = (_Float16)a1;
    *(half2_t*)&S[sb2 + n] = r;
  }
}

// ---------------- K3: in-place exclusive scan over chunks ----------------
__global__ __launch_bounds__(512) void k3_scan(__half* __restrict__ S,
                                               const float* __restrict__ cdec) {
  const int sq = blockIdx.x >> 3, h = blockIdx.x & 7, t = threadIdx.x;
  float carry = 0.f;
  for (int c = 0; c < NCHUNK; ++c) {
    size_t idx = (size_t)(sq * NCHUNK + c) * 4096 + h * 512 + t;
    float s = __half2float(S[idx]);
    S[idx] = __float2half(carry);
    carry = carry * cdec[(sq * NCHUNK + c) * 8 + h] + s;
  }
}

// ---------------- K4: output pass — MFMA for inproj/z/G/Yo/Wout ----------------
// MFMA 16x16x32 f16 conventions used (gfx950):
//   A frag: lane holds A[row = lane&15][k = (lane>>4)*8 + j], j=0..7 (f16x8, ds_read_b128)
//   B frag: lane holds B[k = (lane>>4)*8 + j][col = lane&15]
//   D frag: lane reg r holds D[row = 4*(lane>>4)+r][col = lane&15]   (verified layout)
__global__ __launch_bounds__(256, 2) void k4_out(
    const __half* __restrict__ u, const float* __restrict__ Win,
    const float* __restrict__ convw, const float* __restrict__ convb,
    const float* __restrict__ dtbias, const float* __restrict__ Alog,
    const float* __restrict__ Dp, const float* __restrict__ rmsw,
    const float* __restrict__ Wout, const float* __restrict__ skip,
    const __half* __restrict__ S, __half* __restrict__ ym) {
  __shared__ __align__(16) _Float16 ur_h[48 * URH];  // 3840 B (rows 34..47 zero)
  __shared__ __align__(16) float CH[34 * CHS];       // 26248 B; overlay after conv:
                                                     //   pv fp16 [64][72] @float 0   (2304 f)
                                                     //   G  f32  [32][33] @float 2304 (1056 f)
                                                     //   scl f32 [32]     @float 3360
  __shared__ __align__(16) __half xch[32 * XC4];     // 13312 B; cols 0..63 xs, 64..127 B->ybuf, 128..191 C
  __shared__ float dtraw[256];                       // dtraw [l][h]; later eac[h*32+l]
  __shared__ float dtv[256], acs[256];
  __shared__ __align__(16) _Float16 zbuf[32 * ZBS];  // 4224 B
  const int c = blockIdx.x, sq = blockIdx.y, t = threadIdx.x;
  const int l0 = c * 32;
  const int lane = t & 63, wvi = t >> 6, g = lane >> 4, c16 = lane & 15;
  const size_t ubase = (size_t)sq * (LSEQ * DM);
  const f32x4 zero4 = {0.f, 0.f, 0.f, 0.f};

  // ---- P0: stage ur (fp16), load B-frags (Win via L2), prefetch S into regs ----
  const size_t sbase = (size_t)(sq * NCHUNK + c) * 4096;
  uint4 sv0, sv1;
  {
    const uint4* sp = (const uint4*)(S + sbase);
    sv0 = sp[t * 2];
    sv1 = sp[t * 2 + 1];
  }
  for (int idx = t; idx < 48 * 32; idx += 256) {
    int r = idx >> 5, dm = idx & 31;
    int l = l0 - 2 + r;
    _Float16 v = (_Float16)0.f;
    if (r < 34 && l >= 0) v = ((const _Float16*)u)[ubase + (size_t)l * DM + dm];
    ur_h[r * URH + dm] = v;
  }
  f16x8 bfr[3];  // inproj N-tiles nt = wvi, wvi+4, wvi+8  (channels nt*16.., Win col 64+..)
#pragma unroll
  for (int i = 0; i < 3; ++i) {
    int col = 64 + (wvi + i * 4) * 16 + c16;
#pragma unroll
    for (int j = 0; j < 8; ++j) bfr[i][j] = (_Float16)Win[(g * 8 + j) * DPROJ + col];
  }
  f16x8 bz;  // z N-tile: cols wvi*16..
  {
    int col = wvi * 16 + c16;
#pragma unroll
    for (int j = 0; j < 8; ++j) bz[j] = (_Float16)Win[(g * 8 + j) * DPROJ + col];
  }
  __syncthreads();

  // ---- P1: MFMA inproj -> CH, z -> zbuf ----
  {
    f16x8 am[3];
#pragma unroll
    for (int mt = 0; mt < 3; ++mt)
      am[mt] = *(const f16x8*)&ur_h[(mt * 16 + c16) * URH + g * 8];
#pragma unroll
    for (int i = 0; i < 3; ++i) {
      int colc = (wvi + i * 4) * 16 + c16;
#pragma unroll
      for (int mt = 0; mt < 3; ++mt) {
        f32x4 acc = __builtin_amdgcn_mfma_f32_16x16x32_f16(am[mt], bfr[i], zero4, 0, 0, 0);
#pragma unroll
        for (int r = 0; r < 4; ++r) {
          int R = mt * 16 + 4 * g + r;
          if (R < 34) CH[R * CHS + colc] = acc[r];
        }
      }
    }
#pragma unroll
    for (int mz = 0; mz < 2; ++mz) {
      f16x8 az = *(const f16x8*)&ur_h[(2 + mz * 16 + c16) * URH + g * 8];
      f32x4 acc = __builtin_amdgcn_mfma_f32_16x16x32_f16(az, bz, zero4, 0, 0, 0);
#pragma unroll
      for (int r = 0; r < 4; ++r) {
        int lY = mz * 16 + 4 * g + r;
        zbuf[lY * ZBS + wvi * 16 + c16] = (_Float16)acc[r];
      }
    }
  }
  __syncthreads();

  // ---- P2: conv+silu -> xch; dtraw via f32 scalar dot (precision-sensitive) ----
  {
    const int ch0 = t & 63, lb = t >> 6;
    float cw[3][3], cb[3];
#pragma unroll
    for (int cr = 0; cr < 3; ++cr) {
      int ch = ch0 + cr * 64;
      cw[cr][0] = convw[ch * 3 + 0];
      cw[cr][1] = convw[ch * 3 + 1];
      cw[cr][2] = convw[ch * 3 + 2];
      cb[cr] = convb[ch];
    }
#pragma unroll
    for (int lr = 0; lr < 8; ++lr) {
      int l = lb + lr * 4;
#pragma unroll
      for (int cr = 0; cr < 3; ++cr) {
        int ch = ch0 + cr * 64;
        float v = CH[l * CHS + ch] * cw[cr][0] + CH[(l + 1) * CHS + ch] * cw[cr][1] +
                  CH[(l + 2) * CHS + ch] * cw[cr][2] + cb[cr];
        xch[l * XC4 + ch] = __float2half(silu_(v));
      }
    }
    int l = t >> 3, h = t & 7;
    float raw = 0.f;
#pragma unroll
    for (int dm = 0; dm < 32; ++dm)
      raw += (float)ur_h[(l + 2) * URH + dm] * Win[dm * DPROJ + 256 + h];
    dtraw[l * 8 + h] = raw;
  }
  __syncthreads();

  // ---- P3: pv <- S regs (CH overlay); dt softplus serial ----
  {
    char* pvb = (char*)CH;
    int hp = t >> 2, part = t & 3;
    *(uint4*)(pvb + hp * 144 + part * 32) = sv0;
    *(uint4*)(pvb + hp * 144 + part * 32 + 16) = sv1;
  }
  if (t < 8) {
    float A = -__expf(Alog[t]);
    float bias = dtbias[t];
    float ac = 0.f;
    for (int l = 0; l < 32; ++l) {
      float raw = dtraw[l * 8 + t] + bias;
      float dt = (raw > 20.f) ? raw : log1pf(__expf(raw));
      dtv[t * 32 + l] = dt;
      ac += dt * A;
      acs[t * 32 + l] = ac;
    }
  }
  __syncthreads();

  // ---- P4: eac table; G = C·B^T via MFMA ----
  float* Gm = CH + 2304;
  {
    float ev = __expf(acs[t]);
    dtraw[t] = ev;  // eac[h*32+l]
    const int mt = wvi >> 1, nt = wvi & 1;
    f32x4 acc = zero4;
#pragma unroll
    for (int kk = 0; kk < 2; ++kk) {
      f16x8 aC = *(const f16x8*)&xch[(mt * 16 + c16) * XC4 + 128 + kk * 32 + g * 8];
      f16x8 bB = *(const f16x8*)&xch[(nt * 16 + c16) * XC4 + 64 + kk * 32 + g * 8];
      acc = __builtin_amdgcn_mfma_f32_16x16x32_f16(aC, bB, acc, 0, 0, 0);
    }
#pragma unroll
    for (int r = 0; r < 4; ++r)
      Gm[(mt * 16 + 4 * g + r) * 33 + nt * 16 + c16] = acc[r];
  }
  __syncthreads();

  // ---- P5: Yd scalar -> ybuf (xch cols 64..127) ----
  {
    const int lY = t & 31, h = t >> 5;
    const float al = acs[h * 32 + lY];
    float accd[8] = {0, 0, 0, 0, 0, 0, 0, 0};
    for (int s2 = 0; s2 <= lY; ++s2) {
      float coef = Gm[lY * 33 + s2] * __expf(al - acs[h * 32 + s2]) * dtv[h * 32 + s2];
      const half2_t* xp = (const half2_t*)&xch[s2 * XC4 + h * 8];
#pragma unroll
      for (int j = 0; j < 4; ++j) {
        half2_t v = xp[j];
        accd[2 * j] += coef * (float)v.x;
        accd[2 * j + 1] += coef * (float)v.y;
      }
    }
#pragma unroll
    for (int p = 0; p < 8; ++p)
      xch[lY * XC4 + 64 + h * 8 + p] = __float2half(accd[p]);
  }
  __syncthreads();

  // ---- P6: Yo = C·PV^T via MFMA, scaled by eac, accumulated into ybuf ----
  {
    const __half* pvh = (const __half*)CH;  // [64][72] fp16
#pragma unroll
    for (int mt = 0; mt < 2; ++mt) {
      f32x4 acc = zero4;
#pragma unroll
      for (int kk = 0; kk < 2; ++kk) {
        f16x8 aC = *(const f16x8*)&xch[(mt * 16 + c16) * XC4 + 128 + kk * 32 + g * 8];
        f16x8 bP = *(const f16x8*)&pvh[(wvi * 16 + c16) * 72 + kk * 32 + g * 8];
        acc = __builtin_amdgcn_mfma_f32_16x16x32_f16(aC, bP, acc, 0, 0, 0);
      }
      int hp = wvi * 16 + c16;
#pragma unroll
      for (int r = 0; r < 4; ++r) {
        int l = mt * 16 + 4 * g + r;
        float e = dtraw[(hp >> 3) * 32 + l];
        __half* yb = &xch[l * XC4 + 64 + hp];
        *yb = __float2half(__half2float(*yb) + acc[r] * e);
      }
    }
  }
  __syncthreads();

  // ---- P7: +D*xs, gate with silu(z) from zbuf ----
  {
    const int hp = t & 63;
    const float dcoef = Dp[hp >> 3];
#pragma unroll
    for (int k = 0; k < 8; ++k) {
      int l = (k * 256 + t) >> 6;
      float y = __half2float(xch[l * XC4 + 64 + hp]) + (float)xch[l * XC4 + hp] * dcoef;
      float z = (float)zbuf[l * ZBS + hp];
      y *= z / (1.f + __expf(-z));
      xch[l * XC4 + 64 + hp] = __float2half(y);
    }
  }
  __syncthreads();

  // ---- P8: RMS scale factors ----
  float* scl = CH + 3360;
  if (t < 32) {
    float s2s = 0.f;
#pragma unroll 16
    for (int hp = 0; hp < 64; ++hp) {
      float v = __half2float(xch[t * XC4 + 64 + hp]);
      s2s += v * v;
    }
    scl[t] = rsqrtf(s2s * (1.f / 64.f) + 1e-5f);
  }
  __syncthreads();

  // ---- P9: apply rms * rmsw ----
  for (int idx = t; idx < 2048; idx += 256) {
    int l = idx >> 6, hp = idx & 63;
    xch[l * XC4 + 64 + hp] =
        __float2half(__half2float(xch[l * XC4 + 64 + hp]) * scl[l] * rmsw[hp]);
  }
  __syncthreads();

  // ---- P10: y @ Wout via MFMA + skip, store ym ----
  {
    const float skipv = skip[0];
    const int mt = wvi >> 1, nt = wvi & 1;
    f32x4 acc = zero4;
#pragma unroll
    for (int kk = 0; kk < 2; ++kk) {
      f16x8 aY = *(const f16x8*)&xch[(mt * 16 + c16) * XC4 + 64 + kk * 32 + g * 8];
      f16x8 bW;
#pragma unroll
      for (int j = 0; j < 8; ++j)
        bW[j] = (_Float16)Wout[(kk * 32 + g * 8 + j) * 32 + nt * 16 + c16];
      acc = __builtin_amdgcn_mfma_f32_16x16x32_f16(aY, bW, acc, 0, 0, 0);
    }
#pragma unroll
    for (int r = 0; r < 4; ++r) {
      int l = mt * 16 + 4 * g + r;
      int dm = nt * 16 + c16;
      size_t gi = ubase + (size_t)(l0 + l) * DM + dm;
      ym[gi] = __float2half(acc[r] + skipv * __half2float(u[gi]));
    }
  }
}

// ---------------- K5: regroup + LN2 + proj(256x256) + bias + transpose ----------------
__global__ __launch_bounds__(256) void k5_ln_proj(const __half* __restrict__ ym,
                                                  const float* __restrict__ lnw,
                                                  const float* __restrict__ lnb,
                                                  const float* __restrict__ pw,
                                                  const float* __restrict__ pb,
                                                  float* __restrict__ outp) {
  __shared__ float yf[8448];  // LN phase: [32][257]; epilogue: res [256][33]
  __shared__ float mu[32], rs[32], wv[256], bv[256];
  const int b = blockIdx.y, l0 = blockIdx.x * 32, t = threadIdx.x;
  wv[t] = lnw[t];
  bv[t] = lnb[t];
  for (int sp = 0; sp < 8; ++sp) {
#pragma unroll
    for (int i = 0; i < 4; ++i) {
      int idx = i * 256 + t;
      int ll = idx >> 5, dm = idx & 31;
      yf[ll * 257 + sp * 32 + dm] =
          __half2float(ym[(((size_t)(sp * B0N + b)) * LSEQ + l0 + ll) * DM + dm]);
    }
  }
  __syncthreads();
  if (t < 32) {
    float s = 0.f, s2 = 0.f;
    for (int ch = 0; ch < 256; ++ch) {
      float v = yf[t * 257 + ch];
      s += v; s2 += v * v;
    }
    float m = s * (1.f / 256.f);
    mu[t] = m;
    rs[t] = rsqrtf(s2 * (1.f / 256.f) - m * m + 1e-5f);
  }
  __syncthreads();
#pragma unroll 8
  for (int i = 0; i < 32; ++i) {
    int idx = i * 256 + t;
    int ll = idx >> 8, ch = idx & 255;
    yf[ll * 257 + ch] = (yf[ll * 257 + ch] - mu[ll]) * rs[ll] * wv[ch] + bv[ch];
  }
  __syncthreads();
  const int llg = t >> 5, og = t & 31;
  float acc[4][8];
#pragma unroll
  for (int k = 0; k < 4; ++k)
#pragma unroll
    for (int j = 0; j < 8; ++j) acc[k][j] = 0.f;
  for (int ch = 0; ch < 256; ++ch) {
    const float4 w0 = *(const float4*)(pw + (size_t)ch * 256 + og * 8);
    const float4 w1 = *(const float4*)(pw + (size_t)ch * 256 + og * 8 + 4);
#pragma unroll
    for (int k = 0; k < 4; ++k) {
      float y = yf[(llg * 4 + k) * 257 + ch];
      acc[k][0] += y * w0.x; acc[k][1] += y * w0.y; acc[k][2] += y * w0.z; acc[k][3] += y * w0.w;
      acc[k][4] += y * w1.x; acc[k][5] += y * w1.y; acc[k][6] += y * w1.z; acc[k][7] += y * w1.w;
    }
  }
  __syncthreads();  // all yf reads done before overlay
  float* res = yf;  // [256][33]
#pragma unroll
  for (int j = 0; j < 8; ++j) {
    float bias = pb[og * 8 + j];
#pragma unroll
    for (int k = 0; k < 4; ++k)
      res[(og * 8 + j) * 33 + llg * 4 + k] = acc[k][j] + bias;
  }
  __syncthreads();
  for (int idx = t; idx < 8192; idx += 256) {
    int o = idx >> 5, l = idx & 31;
    outp[((size_t)(b * 256 + o)) * LSEQ + l0 + l] = res[o * 33 + l];
  }
}

extern "C" void kernel_launch(void* const* d_in, const int* in_sizes, int n_in,
                              void* d_out, int out_size, void* d_ws, size_t ws_size,
                              hipStream_t stream) {
  (void)in_sizes; (void)n_in; (void)out_size;
  const float* x     = (const float*)d_in[0];
  const float* lnw   = (const float*)d_in[1];
  const float* lnb   = (const float*)d_in[2];
  const float* skip  = (const float*)d_in[3];
  const float* pw    = (const float*)d_in[4];
  const float* pb    = (const float*)d_in[5];
  const float* Win   = (const float*)d_in[6];
  const float* convw = (const float*)d_in[7];
  const float* convb = (const float*)d_in[8];
  const float* dtb   = (const float*)d_in[9];
  const float* Alog  = (const float*)d_in[10];
  const float* Dp    = (const float*)d_in[11];
  const float* rmsw  = (const float*)d_in[12];
  const float* Wout  = (const float*)d_in[13];
  float* outp = (float*)d_out;

  // workspace layout (fp16 tensors): total 227,082,240 B (ws cap proven < 491 MB in R1)
  const size_t NEED = 227082240ull;
  if (ws_size < NEED) return;
  char* ws = (char*)d_ws;
  __half* u    = (__half*)ws;                    //  37,748,736 B
  __half* S    = (__half*)(ws + 37748736);       // 150,994,944 B
  float*  cdec = (float*)(ws + 188743680);       //     589,824 B
  __half* ym   = (__half*)(ws + 189333504);      //  37,748,736 B

  k1_ln_split<<<dim3(288, 8), 256, 0, stream>>>(x, lnw, lnb, u);
  k2_states<<<dim3(288, 64), 256, 0, stream>>>(u, Win, convw, convb, dtb, Alog, S, cdec);
  k3_scan<<<dim3(512), 512, 0, stream>>>(S, cdec);
  k4_out<<<dim3(288, 64), 256, 0, stream>>>(u, Win, convw, convb, dtb, Alog, Dp, rmsw,
                                            Wout, skip, S, ym);
  k5_ln_proj<<<dim3(288, 8), 256, 0, stream>>>(ym, lnw, lnb, pw, pb, outp);
}

// Round 3
// 1230.651 us; speedup vs baseline: 1.7771x; 1.4070x over previous
//
#include <hip/hip_runtime.h>
#include <hip/hip_fp16.h>
#include <math.h>

typedef unsigned short u16;
typedef unsigned int u32;
typedef _Float16 half2_t __attribute__((ext_vector_type(2)));
typedef _Float16 f16x8 __attribute__((ext_vector_type(8)));
typedef float f32x4 __attribute__((ext_vector_type(4)));

#define B0N 8
#define LSEQ 9216
#define NSEQ 64
#define NCHUNK 288
#define DM 32
#define DPROJ 264
#define CONVCH 192
#define XC4 208   // k4 xc row stride (fp16, 416B rows -> 16B-aligned for ds_read_b128)
#define URH 40    // ur row stride (fp16, 80B rows -> 16B-aligned, 2-way banks)
#define CHS 193   // k4 CH row stride (f32)
#define ZBS 66    // k4 zbuf row stride (fp16)
#define CH2S 129  // k2 CH row stride (f32)
#define TTS 40    // k2 transposed xs/B/A row stride (fp16, 80B rows)

#ifndef __has_builtin
#define __has_builtin(x) 0
#endif

__device__ __forceinline__ float silu_(float v) { return v / (1.f + __expf(-v)); }

__device__ __forceinline__ float fdot2_(half2_t a, half2_t b, float c) {
#if __has_builtin(__builtin_amdgcn_fdot2)
  return __builtin_amdgcn_fdot2(a, b, c, false);
#else
  return c + (float)a.x * (float)b.x + (float)a.y * (float)b.y;
#endif
}

// ---------------- K1: LayerNorm(256) + split -> u (64,9216,32) fp16 ----------------
__global__ __launch_bounds__(256) void k1_ln_split(const float* __restrict__ x,
                                                   const float* __restrict__ lnw,
                                                   const float* __restrict__ lnb,
                                                   __half* __restrict__ u) {
  __shared__ float tile[256 * 33];  // [c][ll]
  __shared__ float mu[32], rs[32], wv[256], bv[256];
  const int b = blockIdx.y, l0 = blockIdx.x * 32, t = threadIdx.x;
  wv[t] = lnw[t];
  bv[t] = lnb[t];
#pragma unroll 4
  for (int i = 0; i < 32; ++i) {
    int c = i * 8 + (t >> 5), ll = t & 31;
    tile[c * 33 + ll] = x[((size_t)b * 256 + c) * LSEQ + l0 + ll];
  }
  __syncthreads();
  if (t < 32) {
    float s = 0.f, s2 = 0.f;
    for (int c = 0; c < 256; ++c) {
      float v = tile[c * 33 + t];
      s += v; s2 += v * v;
    }
    float m = s * (1.f / 256.f);
    mu[t] = m;
    rs[t] = rsqrtf(s2 * (1.f / 256.f) - m * m + 1e-5f);
  }
  __syncthreads();
#pragma unroll 4
  for (int i = 0; i < 32; ++i) {
    int sp = i >> 2, sub = i & 3;
    int ll = sub * 8 + (t >> 5), dm = t & 31;
    int c = sp * 32 + dm;
    float v = (tile[c * 33 + ll] - mu[ll]) * rs[ll] * wv[c] + bv[c];
    u[(((size_t)(sp * B0N + b)) * LSEQ + l0 + ll) * DM + dm] = __float2half(v);
  }
}

// ---------------- K2: in-proj + conv + dt + per-chunk states (MFMA) ----------------
// Only channels 0..127 (xs + B) are needed here; C (128..191) is consumed only by k4.
__global__ __launch_bounds__(256, 2) void k2_states(
    const __half* __restrict__ u, const float* __restrict__ Win,
    const float* __restrict__ convw, const float* __restrict__ convb,
    const float* __restrict__ dtbias, const float* __restrict__ Alog,
    __half* __restrict__ S, float* __restrict__ cdec) {
  __shared__ __align__(16) _Float16 ur_h[48 * URH];  // 3840 B (rows 34..47 zero)
  __shared__ __align__(16) float CH2[34 * CH2S];     // 17544 B; overlay after conv:
                                                     //   Ah fp16 [64][40]  @byte 0    (5120 B)
                                                     //   Sout fp16 [64][72] @byte 5120 (9216 B)
  __shared__ __align__(16) _Float16 xst[64 * TTS];   // 5120 B  xs transposed [hp][l]
  __shared__ __align__(16) _Float16 Bt[64 * TTS];    // 5120 B  B transposed [n][l]
  __shared__ float dtraw[256], dtv[256], acs[256], wv2[256];
  const int c = blockIdx.x, sq = blockIdx.y, t = threadIdx.x;
  const int l0 = c * 32;
  const int lane = t & 63, wvi = t >> 6, g = lane >> 4, c16 = lane & 15;
  const size_t ubase = (size_t)sq * (LSEQ * DM);
  const f32x4 zero4 = {0.f, 0.f, 0.f, 0.f};

  // ---- P0: stage ur (fp16); load Win B-frags (cols 64..191 -> channels 0..127) ----
  for (int idx = t; idx < 48 * 32; idx += 256) {
    int r = idx >> 5, dm = idx & 31;
    int l = l0 - 2 + r;
    _Float16 v = (_Float16)0.f;
    if (r < 34 && l >= 0) v = ((const _Float16*)u)[ubase + (size_t)l * DM + dm];
    ur_h[r * URH + dm] = v;
  }
  f16x8 bfr[2];  // N-tiles nt = wvi, wvi+4
#pragma unroll
  for (int i = 0; i < 2; ++i) {
    int col = 64 + (wvi + i * 4) * 16 + c16;
#pragma unroll
    for (int j = 0; j < 8; ++j) bfr[i][j] = (_Float16)Win[(g * 8 + j) * DPROJ + col];
  }
  __syncthreads();

  // ---- P1: MFMA inproj -> CH2 (34 rows x 128 channels) ----
  {
    f16x8 am[3];
#pragma unroll
    for (int mt = 0; mt < 3; ++mt)
      am[mt] = *(const f16x8*)&ur_h[(mt * 16 + c16) * URH + g * 8];
#pragma unroll
    for (int i = 0; i < 2; ++i) {
      int colc = (wvi + i * 4) * 16 + c16;
#pragma unroll
      for (int mt = 0; mt < 3; ++mt) {
        f32x4 acc = __builtin_amdgcn_mfma_f32_16x16x32_f16(am[mt], bfr[i], zero4, 0, 0, 0);
#pragma unroll
        for (int r = 0; r < 4; ++r) {
          int R = mt * 16 + 4 * g + r;
          if (R < 34) CH2[R * CH2S + colc] = acc[r];
        }
      }
    }
  }
  __syncthreads();

  // ---- P2: conv+silu -> xst/Bt (transposed); dtraw via f32 scalar dot ----
  {
    const int ch0 = t & 63, lb = t >> 6;
    float cw[2][3], cb[2];
#pragma unroll
    for (int cr = 0; cr < 2; ++cr) {
      int ch = ch0 + cr * 64;
      cw[cr][0] = convw[ch * 3 + 0];
      cw[cr][1] = convw[ch * 3 + 1];
      cw[cr][2] = convw[ch * 3 + 2];
      cb[cr] = convb[ch];
    }
#pragma unroll
    for (int lr = 0; lr < 8; ++lr) {
      int l = lb + lr * 4;
#pragma unroll
      for (int cr = 0; cr < 2; ++cr) {
        int ch = ch0 + cr * 64;
        float v = CH2[l * CH2S + ch] * cw[cr][0] + CH2[(l + 1) * CH2S + ch] * cw[cr][1] +
                  CH2[(l + 2) * CH2S + ch] * cw[cr][2] + cb[cr];
        _Float16 sv = (_Float16)silu_(v);
        if (cr == 0) xst[ch * TTS + l] = sv;
        else Bt[(ch - 64) * TTS + l] = sv;
      }
    }
    int l = t >> 3, h = t & 7;
    float raw = 0.f;
#pragma unroll
    for (int dm = 0; dm < 32; ++dm)
      raw += (float)ur_h[(l + 2) * URH + dm] * Win[dm * DPROJ + 256 + h];
    dtraw[l * 8 + h] = raw;
  }
  __syncthreads();

  // ---- P3: dt softplus serial + cdec ----
  if (t < 8) {
    float A = -__expf(Alog[t]);
    float bias = dtbias[t];
    float ac = 0.f;
    for (int l = 0; l < 32; ++l) {
      float raw = dtraw[l * 8 + t] + bias;
      float dt = (raw > 20.f) ? raw : log1pf(__expf(raw));
      dtv[t * 32 + l] = dt;
      ac += dt * A;
      acs[t * 32 + l] = ac;
    }
    cdec[(sq * NCHUNK + c) * 8 + t] = __expf(ac);
  }
  __syncthreads();

  // ---- P4: wv2; build A[hp][l] = wv2[h][l]*xs[l][hp] (fp16, CH2 overlay) ----
  _Float16* Ah = (_Float16*)CH2;
  {
    int h = t >> 5;
    wv2[t] = __expf(acs[h * 32 + 31] - acs[t]) * dtv[t];
  }
  __syncthreads();
  {
    const int hp = t >> 2, lb2 = (t & 3) * 8;
    const float* w = &wv2[(hp >> 3) * 32 + lb2];
    const _Float16* xr = &xst[hp * TTS + lb2];
    _Float16* ar = &Ah[hp * TTS + lb2];
#pragma unroll
    for (int i = 0; i < 8; ++i) ar[i] = (_Float16)((float)xr[i] * w[i]);
  }
  __syncthreads();

  // ---- P5: states MFMA S[hp][n] = A·B -> Sout, then coalesced global store ----
  __half* Sout = (__half*)((char*)CH2 + 5120);  // [64][72] fp16
  {
    const int mt = wvi;
    f16x8 aS = *(const f16x8*)&Ah[(mt * 16 + c16) * TTS + g * 8];
#pragma unroll
    for (int nt = 0; nt < 4; ++nt) {
      f16x8 bS = *(const f16x8*)&Bt[(nt * 16 + c16) * TTS + g * 8];
      f32x4 acc = __builtin_amdgcn_mfma_f32_16x16x32_f16(aS, bS, zero4, 0, 0, 0);
#pragma unroll
      for (int r = 0; r < 4; ++r)
        Sout[(mt * 16 + 4 * g + r) * 72 + nt * 16 + c16] = __float2half(acc[r]);
    }
  }
  __syncthreads();
  const size_t sbase = (size_t)(sq * NCHUNK + c) * 4096;
#pragma unroll
  for (int i = 0; i < 2; ++i) {
    int idx = i * 256 + t;
    int hp = idx >> 3, part = idx & 7;
    *(uint4*)(S + sbase + hp * 64 + part * 8) = *(const uint4*)&Sout[hp * 72 + part * 8];
  }
}

// ---------------- K3: in-place exclusive scan over chunks ----------------
__global__ __launch_bounds__(512) void k3_scan(__half* __restrict__ S,
                                               const float* __restrict__ cdec) {
  const int sq = blockIdx.x >> 3, h = blockIdx.x & 7, t = threadIdx.x;
  float carry = 0.f;
  for (int c = 0; c < NCHUNK; ++c) {
    size_t idx = (size_t)(sq * NCHUNK + c) * 4096 + h * 512 + t;
    float s = __half2float(S[idx]);
    S[idx] = __float2half(carry);
    carry = carry * cdec[(sq * NCHUNK + c) * 8 + h] + s;
  }
}

// ---------------- K4: output pass — MFMA for inproj/z/G/Yo/Wout ----------------
// MFMA 16x16x32 f16 conventions used (gfx950):
//   A frag: lane holds A[row = lane&15][k = (lane>>4)*8 + j], j=0..7 (f16x8, ds_read_b128)
//   B frag: lane holds B[k = (lane>>4)*8 + j][col = lane&15]
//   D frag: lane reg r holds D[row = 4*(lane>>4)+r][col = lane&15]   (verified layout)
__global__ __launch_bounds__(256, 2) void k4_out(
    const __half* __restrict__ u, const float* __restrict__ Win,
    const float* __restrict__ convw, const float* __restrict__ convb,
    const float* __restrict__ dtbias, const float* __restrict__ Alog,
    const float* __restrict__ Dp, const float* __restrict__ rmsw,
    const float* __restrict__ Wout, const float* __restrict__ skip,
    const __half* __restrict__ S, __half* __restrict__ ym) {
  __shared__ __align__(16) _Float16 ur_h[48 * URH];  // 3840 B (rows 34..47 zero)
  __shared__ __align__(16) float CH[34 * CHS];       // 26248 B; overlay after conv:
                                                     //   pv fp16 [64][72] @float 0   (2304 f)
                                                     //   G  f32  [32][33] @float 2304 (1056 f)
                                                     //   scl f32 [32]     @float 3360
  __shared__ __align__(16) __half xch[32 * XC4];     // 13312 B; cols 0..63 xs, 64..127 B->ybuf, 128..191 C
  __shared__ float dtraw[256];                       // dtraw [l][h]; later eac[h*32+l]
  __shared__ float dtv[256], acs[256];
  __shared__ __align__(16) _Float16 zbuf[32 * ZBS];  // 4224 B
  const int c = blockIdx.x, sq = blockIdx.y, t = threadIdx.x;
  const int l0 = c * 32;
  const int lane = t & 63, wvi = t >> 6, g = lane >> 4, c16 = lane & 15;
  const size_t ubase = (size_t)sq * (LSEQ * DM);
  const f32x4 zero4 = {0.f, 0.f, 0.f, 0.f};

  // ---- P0: stage ur (fp16), load B-frags (Win via L2), prefetch S into regs ----
  const size_t sbase = (size_t)(sq * NCHUNK + c) * 4096;
  uint4 sv0, sv1;
  {
    const uint4* sp = (const uint4*)(S + sbase);
    sv0 = sp[t * 2];
    sv1 = sp[t * 2 + 1];
  }
  for (int idx = t; idx < 48 * 32; idx += 256) {
    int r = idx >> 5, dm = idx & 31;
    int l = l0 - 2 + r;
    _Float16 v = (_Float16)0.f;
    if (r < 34 && l >= 0) v = ((const _Float16*)u)[ubase + (size_t)l * DM + dm];
    ur_h[r * URH + dm] = v;
  }
  f16x8 bfr[3];  // inproj N-tiles nt = wvi, wvi+4, wvi+8  (channels nt*16.., Win col 64+..)
#pragma unroll
  for (int i = 0; i < 3; ++i) {
    int col = 64 + (wvi + i * 4) * 16 + c16;
#pragma unroll
    for (int j = 0; j < 8; ++j) bfr[i][j] = (_Float16)Win[(g * 8 + j) * DPROJ + col];
  }
  f16x8 bz;  // z N-tile: cols wvi*16..
  {
    int col = wvi * 16 + c16;
#pragma unroll
    for (int j = 0; j < 8; ++j) bz[j] = (_Float16)Win[(g * 8 + j) * DPROJ + col];
  }
  __syncthreads();

  // ---- P1: MFMA inproj -> CH, z -> zbuf ----
  {
    f16x8 am[3];
#pragma unroll
    for (int mt = 0; mt < 3; ++mt)
      am[mt] = *(const f16x8*)&ur_h[(mt * 16 + c16) * URH + g * 8];
#pragma unroll
    for (int i = 0; i < 3; ++i) {
      int colc = (wvi + i * 4) * 16 + c16;
#pragma unroll
      for (int mt = 0; mt < 3; ++mt) {
        f32x4 acc = __builtin_amdgcn_mfma_f32_16x16x32_f16(am[mt], bfr[i], zero4, 0, 0, 0);
#pragma unroll
        for (int r = 0; r < 4; ++r) {
          int R = mt * 16 + 4 * g + r;
          if (R < 34) CH[R * CHS + colc] = acc[r];
        }
      }
    }
#pragma unroll
    for (int mz = 0; mz < 2; ++mz) {
      f16x8 az = *(const f16x8*)&ur_h[(2 + mz * 16 + c16) * URH + g * 8];
      f32x4 acc = __builtin_amdgcn_mfma_f32_16x16x32_f16(az, bz, zero4, 0, 0, 0);
#pragma unroll
      for (int r = 0; r < 4; ++r) {
        int lY = mz * 16 + 4 * g + r;
        zbuf[lY * ZBS + wvi * 16 + c16] = (_Float16)acc[r];
      }
    }
  }
  __syncthreads();

  // ---- P2: conv+silu -> xch; dtraw via f32 scalar dot (precision-sensitive) ----
  {
    const int ch0 = t & 63, lb = t >> 6;
    float cw[3][3], cb[3];
#pragma unroll
    for (int cr = 0; cr < 3; ++cr) {
      int ch = ch0 + cr * 64;
      cw[cr][0] = convw[ch * 3 + 0];
      cw[cr][1] = convw[ch * 3 + 1];
      cw[cr][2] = convw[ch * 3 + 2];
      cb[cr] = convb[ch];
    }
#pragma unroll
    for (int lr = 0; lr < 8; ++lr) {
      int l = lb + lr * 4;
#pragma unroll
      for (int cr = 0; cr < 3; ++cr) {
        int ch = ch0 + cr * 64;
        float v = CH[l * CHS + ch] * cw[cr][0] + CH[(l + 1) * CHS + ch] * cw[cr][1] +
                  CH[(l + 2) * CHS + ch] * cw[cr][2] + cb[cr];
        xch[l * XC4 + ch] = __float2half(silu_(v));
      }
    }
    int l = t >> 3, h = t & 7;
    float raw = 0.f;
#pragma unroll
    for (int dm = 0; dm < 32; ++dm)
      raw += (float)ur_h[(l + 2) * URH + dm] * Win[dm * DPROJ + 256 + h];
    dtraw[l * 8 + h] = raw;
  }
  __syncthreads();

  // ---- P3: pv <- S regs (CH overlay); dt softplus serial ----
  {
    char* pvb = (char*)CH;
    int hp = t >> 2, part = t & 3;
    *(uint4*)(pvb + hp * 144 + part * 32) = sv0;
    *(uint4*)(pvb + hp * 144 + part * 32 + 16) = sv1;
  }
  if (t < 8) {
    float A = -__expf(Alog[t]);
    float bias = dtbias[t];
    float ac = 0.f;
    for (int l = 0; l < 32; ++l) {
      float raw = dtraw[l * 8 + t] + bias;
      float dt = (raw > 20.f) ? raw : log1pf(__expf(raw));
      dtv[t * 32 + l] = dt;
      ac += dt * A;
      acs[t * 32 + l] = ac;
    }
  }
  __syncthreads();

  // ---- P4: eac table; G = C·B^T via MFMA ----
  float* Gm = CH + 2304;
  {
    float ev = __expf(acs[t]);
    dtraw[t] = ev;  // eac[h*32+l]
    const int mt = wvi >> 1, nt = wvi & 1;
    f32x4 acc = zero4;
#pragma unroll
    for (int kk = 0; kk < 2; ++kk) {
      f16x8 aC = *(const f16x8*)&xch[(mt * 16 + c16) * XC4 + 128 + kk * 32 + g * 8];
      f16x8 bB = *(const f16x8*)&xch[(nt * 16 + c16) * XC4 + 64 + kk * 32 + g * 8];
      acc = __builtin_amdgcn_mfma_f32_16x16x32_f16(aC, bB, acc, 0, 0, 0);
    }
#pragma unroll
    for (int r = 0; r < 4; ++r)
      Gm[(mt * 16 + 4 * g + r) * 33 + nt * 16 + c16] = acc[r];
  }
  __syncthreads();

  // ---- P5: Yd scalar -> ybuf (xch cols 64..127) ----
  {
    const int lY = t & 31, h = t >> 5;
    const float al = acs[h * 32 + lY];
    float accd[8] = {0, 0, 0, 0, 0, 0, 0, 0};
    for (int s2 = 0; s2 <= lY; ++s2) {
      float coef = Gm[lY * 33 + s2] * __expf(al - acs[h * 32 + s2]) * dtv[h * 32 + s2];
      const half2_t* xp = (const half2_t*)&xch[s2 * XC4 + h * 8];
#pragma unroll
      for (int j = 0; j < 4; ++j) {
        half2_t v = xp[j];
        accd[2 * j] += coef * (float)v.x;
        accd[2 * j + 1] += coef * (float)v.y;
      }
    }
#pragma unroll
    for (int p = 0; p < 8; ++p)
      xch[lY * XC4 + 64 + h * 8 + p] = __float2half(accd[p]);
  }
  __syncthreads();

  // ---- P6: Yo = C·PV^T via MFMA, scaled by eac, accumulated into ybuf ----
  {
    const __half* pvh = (const __half*)CH;  // [64][72] fp16
#pragma unroll
    for (int mt = 0; mt < 2; ++mt) {
      f32x4 acc = zero4;
#pragma unroll
      for (int kk = 0; kk < 2; ++kk) {
        f16x8 aC = *(const f16x8*)&xch[(mt * 16 + c16) * XC4 + 128 + kk * 32 + g * 8];
        f16x8 bP = *(const f16x8*)&pvh[(wvi * 16 + c16) * 72 + kk * 32 + g * 8];
        acc = __builtin_amdgcn_mfma_f32_16x16x32_f16(aC, bP, acc, 0, 0, 0);
      }
      int hp = wvi * 16 + c16;
#pragma unroll
      for (int r = 0; r < 4; ++r) {
        int l = mt * 16 + 4 * g + r;
        float e = dtraw[(hp >> 3) * 32 + l];
        __half* yb = &xch[l * XC4 + 64 + hp];
        *yb = __float2half(__half2float(*yb) + acc[r] * e);
      }
    }
  }
  __syncthreads();

  // ---- P7: +D*xs, gate with silu(z) from zbuf ----
  {
    const int hp = t & 63;
    const float dcoef = Dp[hp >> 3];
#pragma unroll
    for (int k = 0; k < 8; ++k) {
      int l = (k * 256 + t) >> 6;
      float y = __half2float(xch[l * XC4 + 64 + hp]) + (float)xch[l * XC4 + hp] * dcoef;
      float z = (float)zbuf[l * ZBS + hp];
      y *= z / (1.f + __expf(-z));
      xch[l * XC4 + 64 + hp] = __float2half(y);
    }
  }
  __syncthreads();

  // ---- P8: RMS scale factors ----
  float* scl = CH + 3360;
  if (t < 32) {
    float s2s = 0.f;
#pragma unroll 16
    for (int hp = 0; hp < 64; ++hp) {
      float v = __half2float(xch[t * XC4 + 64 + hp]);
      s2s += v * v;
    }
    scl[t] = rsqrtf(s2s * (1.f / 64.f) + 1e-5f);
  }
  __syncthreads();

  // ---- P9: apply rms * rmsw ----
  for (int idx = t; idx < 2048; idx += 256) {
    int l = idx >> 6, hp = idx & 63;
    xch[l * XC4 + 64 + hp] =
        __float2half(__half2float(xch[l * XC4 + 64 + hp]) * scl[l] * rmsw[hp]);
  }
  __syncthreads();

  // ---- P10: y @ Wout via MFMA + skip, store ym ----
  {
    const float skipv = skip[0];
    const int mt = wvi >> 1, nt = wvi & 1;
    f32x4 acc = zero4;
#pragma unroll
    for (int kk = 0; kk < 2; ++kk) {
      f16x8 aY = *(const f16x8*)&xch[(mt * 16 + c16) * XC4 + 64 + kk * 32 + g * 8];
      f16x8 bW;
#pragma unroll
      for (int j = 0; j < 8; ++j)
        bW[j] = (_Float16)Wout[(kk * 32 + g * 8 + j) * 32 + nt * 16 + c16];
      acc = __builtin_amdgcn_mfma_f32_16x16x32_f16(aY, bW, acc, 0, 0, 0);
    }
#pragma unroll
    for (int r = 0; r < 4; ++r) {
      int l = mt * 16 + 4 * g + r;
      int dm = nt * 16 + c16;
      size_t gi = ubase + (size_t)(l0 + l) * DM + dm;
      ym[gi] = __float2half(acc[r] + skipv * __half2float(u[gi]));
    }
  }
}

// ---------------- K5: regroup + LN2 + proj(256x256) + bias + transpose ----------------
__global__ __launch_bounds__(256) void k5_ln_proj(const __half* __restrict__ ym,
                                                  const float* __restrict__ lnw,
                                                  const float* __restrict__ lnb,
                                                  const float* __restrict__ pw,
                                                  const float* __restrict__ pb,
                                                  float* __restrict__ outp) {
  __shared__ float yf[8448];  // LN phase: [32][257]; epilogue: res [256][33]
  __shared__ float mu[32], rs[32], wv[256], bv[256];
  const int b = blockIdx.y, l0 = blockIdx.x * 32, t = threadIdx.x;
  wv[t] = lnw[t];
  bv[t] = lnb[t];
  for (int sp = 0; sp < 8; ++sp) {
#pragma unroll
    for (int i = 0; i < 4; ++i) {
      int idx = i * 256 + t;
      int ll = idx >> 5, dm = idx & 31;
      yf[ll * 257 + sp * 32 + dm] =
          __half2float(ym[(((size_t)(sp * B0N + b)) * LSEQ + l0 + ll) * DM + dm]);
    }
  }
  __syncthreads();
  if (t < 32) {
    float s = 0.f, s2 = 0.f;
    for (int ch = 0; ch < 256; ++ch) {
      float v = yf[t * 257 + ch];
      s += v; s2 += v * v;
    }
    float m = s * (1.f / 256.f);
    mu[t] = m;
    rs[t] = rsqrtf(s2 * (1.f / 256.f) - m * m + 1e-5f);
  }
  __syncthreads();
#pragma unroll 8
  for (int i = 0; i < 32; ++i) {
    int idx = i * 256 + t;
    int ll = idx >> 8, ch = idx & 255;
    yf[ll * 257 + ch] = (yf[ll * 257 + ch] - mu[ll]) * rs[ll] * wv[ch] + bv[ch];
  }
  __syncthreads();
  const int llg = t >> 5, og = t & 31;
  float acc[4][8];
#pragma unroll
  for (int k = 0; k < 4; ++k)
#pragma unroll
    for (int j = 0; j < 8; ++j) acc[k][j] = 0.f;
  for (int ch = 0; ch < 256; ++ch) {
    const float4 w0 = *(const float4*)(pw + (size_t)ch * 256 + og * 8);
    const float4 w1 = *(const float4*)(pw + (size_t)ch * 256 + og * 8 + 4);
#pragma unroll
    for (int k = 0; k < 4; ++k) {
      float y = yf[(llg * 4 + k) * 257 + ch];
      acc[k][0] += y * w0.x; acc[k][1] += y * w0.y; acc[k][2] += y * w0.z; acc[k][3] += y * w0.w;
      acc[k][4] += y * w1.x; acc[k][5] += y * w1.y; acc[k][6] += y * w1.z; acc[k][7] += y * w1.w;
    }
  }
  __syncthreads();  // all yf reads done before overlay
  float* res = yf;  // [256][33]
#pragma unroll
  for (int j = 0; j < 8; ++j) {
    float bias = pb[og * 8 + j];
#pragma unroll
    for (int k = 0; k < 4; ++k)
      res[(og * 8 + j) * 33 + llg * 4 + k] = acc[k][j] + bias;
  }
  __syncthreads();
  for (int idx = t; idx < 8192; idx += 256) {
    int o = idx >> 5, l = idx & 31;
    outp[((size_t)(b * 256 + o)) * LSEQ + l0 + l] = res[o * 33 + l];
  }
}

extern "C" void kernel_launch(void* const* d_in, const int* in_sizes, int n_in,
                              void* d_out, int out_size, void* d_ws, size_t ws_size,
                              hipStream_t stream) {
  (void)in_sizes; (void)n_in; (void)out_size;
  const float* x     = (const float*)d_in[0];
  const float* lnw   = (const float*)d_in[1];
  const float* lnb   = (const float*)d_in[2];
  const float* skip  = (const float*)d_in[3];
  const float* pw    = (const float*)d_in[4];
  const float* pb    = (const float*)d_in[5];
  const float* Win   = (const float*)d_in[6];
  const float* convw = (const float*)d_in[7];
  const float* convb = (const float*)d_in[8];
  const float* dtb   = (const float*)d_in[9];
  const float* Alog  = (const float*)d_in[10];
  const float* Dp    = (const float*)d_in[11];
  const float* rmsw  = (const float*)d_in[12];
  const float* Wout  = (const float*)d_in[13];
  float* outp = (float*)d_out;

  // workspace layout (fp16 tensors): total 227,082,240 B (ws cap proven < 491 MB in R1)
  const size_t NEED = 227082240ull;
  if (ws_size < NEED) return;
  char* ws = (char*)d_ws;
  __half* u    = (__half*)ws;                    //  37,748,736 B
  __half* S    = (__half*)(ws + 37748736);       // 150,994,944 B
  float*  cdec = (float*)(ws + 188743680);       //     589,824 B
  __half* ym   = (__half*)(ws + 189333504);      //  37,748,736 B

  k1_ln_split<<<dim3(288, 8), 256, 0, stream>>>(x, lnw, lnb, u);
  k2_states<<<dim3(288, 64), 256, 0, stream>>>(u, Win, convw, convb, dtb, Alog, S, cdec);
  k3_scan<<<dim3(512), 512, 0, stream>>>(S, cdec);
  k4_out<<<dim3(288, 64), 256, 0, stream>>>(u, Win, convw, convb, dtb, Alog, Dp, rmsw,
                                            Wout, skip, S, ym);
  k5_ln_proj<<<dim3(288, 8), 256, 0, stream>>>(ym, lnw, lnb, pw, pb, outp);
}

// Round 4
// 1143.088 us; speedup vs baseline: 1.9132x; 1.0766x over previous
//
#include <hip/hip_runtime.h>
#include <hip/hip_fp16.h>
#include <math.h>

typedef unsigned short u16;
typedef unsigned int u32;
typedef _Float16 half2_t __attribute__((ext_vector_type(2)));
typedef _Float16 f16x8 __attribute__((ext_vector_type(8)));
typedef float f32x4 __attribute__((ext_vector_type(4)));

#define B0N 8
#define LSEQ 9216
#define NSEQ 64
#define NCHUNK 288
#define DM 32
#define DPROJ 264
#define CONVCH 192
#define XC4 208   // k4 xc row stride (fp16, 416B rows -> 16B-aligned for ds_read_b128)
#define URH 40    // ur row stride (fp16, 80B rows -> 16B-aligned, 2-way banks)
#define CHH 204   // k4 CH row stride (fp16; 408B rows; D-row groups land on distinct banks)
#define ZBS 66    // k4 zbuf row stride (fp16)
#define CH2S 129  // k2 CH row stride (f32)
#define TTS 40    // k2 transposed xs/B/A row stride (fp16, 80B rows)

#ifndef __has_builtin
#define __has_builtin(x) 0
#endif

__device__ __forceinline__ float silu_(float v) { return v / (1.f + __expf(-v)); }

__device__ __forceinline__ float fdot2_(half2_t a, half2_t b, float c) {
#if __has_builtin(__builtin_amdgcn_fdot2)
  return __builtin_amdgcn_fdot2(a, b, c, false);
#else
  return c + (float)a.x * (float)b.x + (float)a.y * (float)b.y;
#endif
}

// ---------------- K1: LayerNorm(256) + split -> u (64,9216,32) fp16 ----------------
__global__ __launch_bounds__(256) void k1_ln_split(const float* __restrict__ x,
                                                   const float* __restrict__ lnw,
                                                   const float* __restrict__ lnb,
                                                   __half* __restrict__ u) {
  __shared__ float tile[256 * 33];  // [c][ll]
  __shared__ float mu[32], rs[32], wv[256], bv[256];
  const int b = blockIdx.y, l0 = blockIdx.x * 32, t = threadIdx.x;
  wv[t] = lnw[t];
  bv[t] = lnb[t];
#pragma unroll 4
  for (int i = 0; i < 32; ++i) {
    int c = i * 8 + (t >> 5), ll = t & 31;
    tile[c * 33 + ll] = x[((size_t)b * 256 + c) * LSEQ + l0 + ll];
  }
  __syncthreads();
  if (t < 32) {
    float s = 0.f, s2 = 0.f;
    for (int c = 0; c < 256; ++c) {
      float v = tile[c * 33 + t];
      s += v; s2 += v * v;
    }
    float m = s * (1.f / 256.f);
    mu[t] = m;
    rs[t] = rsqrtf(s2 * (1.f / 256.f) - m * m + 1e-5f);
  }
  __syncthreads();
#pragma unroll 4
  for (int i = 0; i < 32; ++i) {
    int sp = i >> 2, sub = i & 3;
    int ll = sub * 8 + (t >> 5), dm = t & 31;
    int c = sp * 32 + dm;
    float v = (tile[c * 33 + ll] - mu[ll]) * rs[ll] * wv[c] + bv[c];
    u[(((size_t)(sp * B0N + b)) * LSEQ + l0 + ll) * DM + dm] = __float2half(v);
  }
}

// ---------------- K2: in-proj + conv + dt + per-chunk states (MFMA) ----------------
// Only channels 0..127 (xs + B) are needed here; C (128..191) is consumed only by k4.
__global__ __launch_bounds__(256, 2) void k2_states(
    const __half* __restrict__ u, const float* __restrict__ Win,
    const float* __restrict__ convw, const float* __restrict__ convb,
    const float* __restrict__ dtbias, const float* __restrict__ Alog,
    __half* __restrict__ S, float* __restrict__ cdec) {
  __shared__ __align__(16) _Float16 ur_h[48 * URH];  // 3840 B (rows 34..47 zero)
  __shared__ __align__(16) float CH2[34 * CH2S];     // 17544 B; overlay after conv:
                                                     //   Ah fp16 [64][40]  @byte 0    (5120 B)
                                                     //   Sout fp16 [64][72] @byte 5120 (9216 B)
  __shared__ __align__(16) _Float16 xst[64 * TTS];   // 5120 B  xs transposed [hp][l]
  __shared__ __align__(16) _Float16 Bt[64 * TTS];    // 5120 B  B transposed [n][l]
  __shared__ float dtraw[256], dtv[256], acs[256], wv2[256];
  const int c = blockIdx.x, sq = blockIdx.y, t = threadIdx.x;
  const int l0 = c * 32;
  const int lane = t & 63, wvi = t >> 6, g = lane >> 4, c16 = lane & 15;
  const size_t ubase = (size_t)sq * (LSEQ * DM);
  const f32x4 zero4 = {0.f, 0.f, 0.f, 0.f};

  // ---- P0: stage ur (fp16); load Win B-frags (cols 64..191 -> channels 0..127) ----
  for (int idx = t; idx < 48 * 32; idx += 256) {
    int r = idx >> 5, dm = idx & 31;
    int l = l0 - 2 + r;
    _Float16 v = (_Float16)0.f;
    if (r < 34 && l >= 0) v = ((const _Float16*)u)[ubase + (size_t)l * DM + dm];
    ur_h[r * URH + dm] = v;
  }
  f16x8 bfr[2];  // N-tiles nt = wvi, wvi+4
#pragma unroll
  for (int i = 0; i < 2; ++i) {
    int col = 64 + (wvi + i * 4) * 16 + c16;
#pragma unroll
    for (int j = 0; j < 8; ++j) bfr[i][j] = (_Float16)Win[(g * 8 + j) * DPROJ + col];
  }
  __syncthreads();

  // ---- P1: MFMA inproj -> CH2 (34 rows x 128 channels) ----
  {
    f16x8 am[3];
#pragma unroll
    for (int mt = 0; mt < 3; ++mt)
      am[mt] = *(const f16x8*)&ur_h[(mt * 16 + c16) * URH + g * 8];
#pragma unroll
    for (int i = 0; i < 2; ++i) {
      int colc = (wvi + i * 4) * 16 + c16;
#pragma unroll
      for (int mt = 0; mt < 3; ++mt) {
        f32x4 acc = __builtin_amdgcn_mfma_f32_16x16x32_f16(am[mt], bfr[i], zero4, 0, 0, 0);
#pragma unroll
        for (int r = 0; r < 4; ++r) {
          int R = mt * 16 + 4 * g + r;
          if (R < 34) CH2[R * CH2S + colc] = acc[r];
        }
      }
    }
  }
  __syncthreads();

  // ---- P2: conv+silu -> xst/Bt (transposed); dtraw via f32 scalar dot ----
  {
    const int ch0 = t & 63, lb = t >> 6;
    float cw[2][3], cb[2];
#pragma unroll
    for (int cr = 0; cr < 2; ++cr) {
      int ch = ch0 + cr * 64;
      cw[cr][0] = convw[ch * 3 + 0];
      cw[cr][1] = convw[ch * 3 + 1];
      cw[cr][2] = convw[ch * 3 + 2];
      cb[cr] = convb[ch];
    }
#pragma unroll
    for (int lr = 0; lr < 8; ++lr) {
      int l = lb + lr * 4;
#pragma unroll
      for (int cr = 0; cr < 2; ++cr) {
        int ch = ch0 + cr * 64;
        float v = CH2[l * CH2S + ch] * cw[cr][0] + CH2[(l + 1) * CH2S + ch] * cw[cr][1] +
                  CH2[(l + 2) * CH2S + ch] * cw[cr][2] + cb[cr];
        _Float16 sv = (_Float16)silu_(v);
        if (cr == 0) xst[ch * TTS + l] = sv;
        else Bt[(ch - 64) * TTS + l] = sv;
      }
    }
    int l = t >> 3, h = t & 7;
    float raw = 0.f;
#pragma unroll
    for (int dm = 0; dm < 32; ++dm)
      raw += (float)ur_h[(l + 2) * URH + dm] * Win[dm * DPROJ + 256 + h];
    dtraw[l * 8 + h] = raw;
  }
  __syncthreads();

  // ---- P3: dt softplus serial + cdec ----
  if (t < 8) {
    float A = -__expf(Alog[t]);
    float bias = dtbias[t];
    float ac = 0.f;
    for (int l = 0; l < 32; ++l) {
      float raw = dtraw[l * 8 + t] + bias;
      float dt = (raw > 20.f) ? raw : log1pf(__expf(raw));
      dtv[t * 32 + l] = dt;
      ac += dt * A;
      acs[t * 32 + l] = ac;
    }
    cdec[(sq * NCHUNK + c) * 8 + t] = __expf(ac);
  }
  __syncthreads();

  // ---- P4: wv2; build A[hp][l] = wv2[h][l]*xs[l][hp] (fp16, CH2 overlay) ----
  _Float16* Ah = (_Float16*)CH2;
  {
    int h = t >> 5;
    wv2[t] = __expf(acs[h * 32 + 31] - acs[t]) * dtv[t];
  }
  __syncthreads();
  {
    const int hp = t >> 2, lb2 = (t & 3) * 8;
    const float* w = &wv2[(hp >> 3) * 32 + lb2];
    const _Float16* xr = &xst[hp * TTS + lb2];
    _Float16* ar = &Ah[hp * TTS + lb2];
#pragma unroll
    for (int i = 0; i < 8; ++i) ar[i] = (_Float16)((float)xr[i] * w[i]);
  }
  __syncthreads();

  // ---- P5: states MFMA S[hp][n] = A·B -> Sout, then coalesced global store ----
  __half* Sout = (__half*)((char*)CH2 + 5120);  // [64][72] fp16
  {
    const int mt = wvi;
    f16x8 aS = *(const f16x8*)&Ah[(mt * 16 + c16) * TTS + g * 8];
#pragma unroll
    for (int nt = 0; nt < 4; ++nt) {
      f16x8 bS = *(const f16x8*)&Bt[(nt * 16 + c16) * TTS + g * 8];
      f32x4 acc = __builtin_amdgcn_mfma_f32_16x16x32_f16(aS, bS, zero4, 0, 0, 0);
#pragma unroll
      for (int r = 0; r < 4; ++r)
        Sout[(mt * 16 + 4 * g + r) * 72 + nt * 16 + c16] = __float2half(acc[r]);
    }
  }
  __syncthreads();
  const size_t sbase = (size_t)(sq * NCHUNK + c) * 4096;
#pragma unroll
  for (int i = 0; i < 2; ++i) {
    int idx = i * 256 + t;
    int hp = idx >> 3, part = idx & 7;
    *(uint4*)(S + sbase + hp * 64 + part * 8) = *(const uint4*)&Sout[hp * 72 + part * 8];
  }
}

// ---------------- K3: in-place exclusive scan over chunks ----------------
__global__ __launch_bounds__(512) void k3_scan(__half* __restrict__ S,
                                               const float* __restrict__ cdec) {
  const int sq = blockIdx.x >> 3, h = blockIdx.x & 7, t = threadIdx.x;
  float carry = 0.f;
  for (int c = 0; c < NCHUNK; ++c) {
    size_t idx = (size_t)(sq * NCHUNK + c) * 4096 + h * 512 + t;
    float s = __half2float(S[idx]);
    S[idx] = __float2half(carry);
    carry = carry * cdec[(sq * NCHUNK + c) * 8 + h] + s;
  }
}

// ---------------- K4: output pass — MFMA for inproj/z/G/Yo/Wout ----------------
// MFMA 16x16x32 f16 conventions used (gfx950):
//   A frag: lane holds A[row = lane&15][k = (lane>>4)*8 + j], j=0..7 (f16x8, ds_read_b128)
//   B frag: lane holds B[k = (lane>>4)*8 + j][col = lane&15]
//   D frag: lane reg r holds D[row = 4*(lane>>4)+r][col = lane&15]   (verified layout)
// CH held in fp16 (conv-input rounding is below the fp16 output-quantization floor)
// -> LDS 38.3 KB -> 4 blocks/CU (was 51.2 KB / 3 blocks).
__global__ __launch_bounds__(256, 4) void k4_out(
    const __half* __restrict__ u, const float* __restrict__ Win,
    const float* __restrict__ convw, const float* __restrict__ convb,
    const float* __restrict__ dtbias, const float* __restrict__ Alog,
    const float* __restrict__ Dp, const float* __restrict__ rmsw,
    const float* __restrict__ Wout, const float* __restrict__ skip,
    const __half* __restrict__ S, __half* __restrict__ ym) {
  __shared__ __align__(16) _Float16 ur_h[48 * URH];   // 3840 B (rows 34..47 zero)
  __shared__ __align__(16) _Float16 CHh[34 * CHH];    // 13872 B; overlay after conv:
                                                      //   pv fp16 [64][72] @byte 0     (9216 B)
                                                      //   G  f32  [32][33] @byte 9216  (4224 B)
                                                      //   scl f32 [32]     @byte 13440 (128 B)
  __shared__ __align__(16) __half xch[32 * XC4];      // 13312 B; cols 0..63 xs, 64..127 B->ybuf, 128..191 C
  __shared__ float dtraw[256];                        // dtraw [l][h]; later eac[h*32+l]
  __shared__ float dtv[256], acs[256];
  __shared__ __align__(16) _Float16 zbuf[32 * ZBS];   // 4224 B
  const int c = blockIdx.x, sq = blockIdx.y, t = threadIdx.x;
  const int l0 = c * 32;
  const int lane = t & 63, wvi = t >> 6, g = lane >> 4, c16 = lane & 15;
  const size_t ubase = (size_t)sq * (LSEQ * DM);
  const f32x4 zero4 = {0.f, 0.f, 0.f, 0.f};

  // ---- P0: stage ur (fp16), load B-frags (Win via L2), prefetch S into regs ----
  const size_t sbase = (size_t)(sq * NCHUNK + c) * 4096;
  uint4 sv0, sv1;
  {
    const uint4* sp = (const uint4*)(S + sbase);
    sv0 = sp[t * 2];
    sv1 = sp[t * 2 + 1];
  }
  for (int idx = t; idx < 48 * 32; idx += 256) {
    int r = idx >> 5, dm = idx & 31;
    int l = l0 - 2 + r;
    _Float16 v = (_Float16)0.f;
    if (r < 34 && l >= 0) v = ((const _Float16*)u)[ubase + (size_t)l * DM + dm];
    ur_h[r * URH + dm] = v;
  }
  f16x8 bfr[3];  // inproj N-tiles nt = wvi, wvi+4, wvi+8  (channels nt*16.., Win col 64+..)
#pragma unroll
  for (int i = 0; i < 3; ++i) {
    int col = 64 + (wvi + i * 4) * 16 + c16;
#pragma unroll
    for (int j = 0; j < 8; ++j) bfr[i][j] = (_Float16)Win[(g * 8 + j) * DPROJ + col];
  }
  f16x8 bz;  // z N-tile: cols wvi*16..
  {
    int col = wvi * 16 + c16;
#pragma unroll
    for (int j = 0; j < 8; ++j) bz[j] = (_Float16)Win[(g * 8 + j) * DPROJ + col];
  }
  __syncthreads();

  // ---- P1: MFMA inproj -> CHh (fp16), z -> zbuf ----
  {
    f16x8 am[3];
#pragma unroll
    for (int mt = 0; mt < 3; ++mt)
      am[mt] = *(const f16x8*)&ur_h[(mt * 16 + c16) * URH + g * 8];
#pragma unroll
    for (int i = 0; i < 3; ++i) {
      int colc = (wvi + i * 4) * 16 + c16;
#pragma unroll
      for (int mt = 0; mt < 3; ++mt) {
        f32x4 acc = __builtin_amdgcn_mfma_f32_16x16x32_f16(am[mt], bfr[i], zero4, 0, 0, 0);
#pragma unroll
        for (int r = 0; r < 4; ++r) {
          int R = mt * 16 + 4 * g + r;
          if (R < 34) CHh[R * CHH + colc] = (_Float16)acc[r];
        }
      }
    }
#pragma unroll
    for (int mz = 0; mz < 2; ++mz) {
      f16x8 az = *(const f16x8*)&ur_h[(2 + mz * 16 + c16) * URH + g * 8];
      f32x4 acc = __builtin_amdgcn_mfma_f32_16x16x32_f16(az, bz, zero4, 0, 0, 0);
#pragma unroll
      for (int r = 0; r < 4; ++r) {
        int lY = mz * 16 + 4 * g + r;
        zbuf[lY * ZBS + wvi * 16 + c16] = (_Float16)acc[r];
      }
    }
  }
  __syncthreads();

  // ---- P2: conv+silu -> xch (rolling 3-tap over 8 consecutive rows);
  //          dtraw via f32 scalar dot (precision-sensitive) ----
  {
    const int ch0 = t & 63, lbq = t >> 6;  // rows lbq*8 .. lbq*8+7
#pragma unroll
    for (int cr = 0; cr < 3; ++cr) {
      int ch = ch0 + cr * 64;
      float w0 = convw[ch * 3 + 0], w1 = convw[ch * 3 + 1], w2 = convw[ch * 3 + 2];
      float cb = convb[ch];
      float a = (float)CHh[(lbq * 8 + 0) * CHH + ch];
      float b = (float)CHh[(lbq * 8 + 1) * CHH + ch];
#pragma unroll
      for (int j = 0; j < 8; ++j) {
        float cn = (float)CHh[(lbq * 8 + j + 2) * CHH + ch];
        float v = a * w0 + b * w1 + cn * w2 + cb;
        xch[(lbq * 8 + j) * XC4 + ch] = __float2half(silu_(v));
        a = b; b = cn;
      }
    }
    int l = t >> 3, h = t & 7;
    float raw = 0.f;
#pragma unroll
    for (int dm = 0; dm < 32; ++dm)
      raw += (float)ur_h[(l + 2) * URH + dm] * Win[dm * DPROJ + 256 + h];
    dtraw[l * 8 + h] = raw;
  }
  __syncthreads();

  // ---- P3: pv <- S regs (CHh overlay); dt softplus serial ----
  {
    char* pvb = (char*)CHh;
    int hp = t >> 2, part = t & 3;
    *(uint4*)(pvb + hp * 144 + part * 32) = sv0;
    *(uint4*)(pvb + hp * 144 + part * 32 + 16) = sv1;
  }
  if (t < 8) {
    float A = -__expf(Alog[t]);
    float bias = dtbias[t];
    float ac = 0.f;
    for (int l = 0; l < 32; ++l) {
      float raw = dtraw[l * 8 + t] + bias;
      float dt = (raw > 20.f) ? raw : log1pf(__expf(raw));
      dtv[t * 32 + l] = dt;
      ac += dt * A;
      acs[t * 32 + l] = ac;
    }
  }
  __syncthreads();

  // ---- P4: eac table; G = C·B^T via MFMA ----
  float* Gm = (float*)((char*)CHh + 9216);
  {
    float ev = __expf(acs[t]);
    dtraw[t] = ev;  // eac[h*32+l]
    const int mt = wvi >> 1, nt = wvi & 1;
    f32x4 acc = zero4;
#pragma unroll
    for (int kk = 0; kk < 2; ++kk) {
      f16x8 aC = *(const f16x8*)&xch[(mt * 16 + c16) * XC4 + 128 + kk * 32 + g * 8];
      f16x8 bB = *(const f16x8*)&xch[(nt * 16 + c16) * XC4 + 64 + kk * 32 + g * 8];
      acc = __builtin_amdgcn_mfma_f32_16x16x32_f16(aC, bB, acc, 0, 0, 0);
    }
#pragma unroll
    for (int r = 0; r < 4; ++r)
      Gm[(mt * 16 + 4 * g + r) * 33 + nt * 16 + c16] = acc[r];
  }
  __syncthreads();

  // ---- P5: Yd scalar -> ybuf (xch cols 64..127) ----
  {
    const int lY = t & 31, h = t >> 5;
    const float al = acs[h * 32 + lY];
    float accd[8] = {0, 0, 0, 0, 0, 0, 0, 0};
    for (int s2 = 0; s2 <= lY; ++s2) {
      float coef = Gm[lY * 33 + s2] * __expf(al - acs[h * 32 + s2]) * dtv[h * 32 + s2];
      const half2_t* xp = (const half2_t*)&xch[s2 * XC4 + h * 8];
#pragma unroll
      for (int j = 0; j < 4; ++j) {
        half2_t v = xp[j];
        accd[2 * j] += coef * (float)v.x;
        accd[2 * j + 1] += coef * (float)v.y;
      }
    }
#pragma unroll
    for (int p = 0; p < 8; ++p)
      xch[lY * XC4 + 64 + h * 8 + p] = __float2half(accd[p]);
  }
  __syncthreads();

  // ---- P6: Yo = C·PV^T via MFMA, scaled by eac, accumulated into ybuf ----
  {
    const __half* pvh = (const __half*)CHh;  // [64][72] fp16
#pragma unroll
    for (int mt = 0; mt < 2; ++mt) {
      f32x4 acc = zero4;
#pragma unroll
      for (int kk = 0; kk < 2; ++kk) {
        f16x8 aC = *(const f16x8*)&xch[(mt * 16 + c16) * XC4 + 128 + kk * 32 + g * 8];
        f16x8 bP = *(const f16x8*)&pvh[(wvi * 16 + c16) * 72 + kk * 32 + g * 8];
        acc = __builtin_amdgcn_mfma_f32_16x16x32_f16(aC, bP, acc, 0, 0, 0);
      }
      int hp = wvi * 16 + c16;
#pragma unroll
      for (int r = 0; r < 4; ++r) {
        int l = mt * 16 + 4 * g + r;
        float e = dtraw[(hp >> 3) * 32 + l];
        __half* yb = &xch[l * XC4 + 64 + hp];
        *yb = __float2half(__half2float(*yb) + acc[r] * e);
      }
    }
  }
  __syncthreads();

  // ---- P7: +D*xs, gate with silu(z) from zbuf ----
  {
    const int hp = t & 63;
    const float dcoef = Dp[hp >> 3];
#pragma unroll
    for (int k = 0; k < 8; ++k) {
      int l = (k * 256 + t) >> 6;
      float y = __half2float(xch[l * XC4 + 64 + hp]) + (float)xch[l * XC4 + hp] * dcoef;
      float z = (float)zbuf[l * ZBS + hp];
      y *= z / (1.f + __expf(-z));
      xch[l * XC4 + 64 + hp] = __float2half(y);
    }
  }
  __syncthreads();

  // ---- P8: RMS scale factors ----
  float* scl = (float*)((char*)CHh + 13440);
  if (t < 32) {
    float s2s = 0.f;
#pragma unroll 16
    for (int hp = 0; hp < 64; ++hp) {
      float v = __half2float(xch[t * XC4 + 64 + hp]);
      s2s += v * v;
    }
    scl[t] = rsqrtf(s2s * (1.f / 64.f) + 1e-5f);
  }
  __syncthreads();

  // ---- P9: apply rms * rmsw ----
  for (int idx = t; idx < 2048; idx += 256) {
    int l = idx >> 6, hp = idx & 63;
    xch[l * XC4 + 64 + hp] =
        __float2half(__half2float(xch[l * XC4 + 64 + hp]) * scl[l] * rmsw[hp]);
  }
  __syncthreads();

  // ---- P10: y @ Wout via MFMA + skip, store ym ----
  {
    const float skipv = skip[0];
    const int mt = wvi >> 1, nt = wvi & 1;
    f32x4 acc = zero4;
#pragma unroll
    for (int kk = 0; kk < 2; ++kk) {
      f16x8 aY = *(const f16x8*)&xch[(mt * 16 + c16) * XC4 + 64 + kk * 32 + g * 8];
      f16x8 bW;
#pragma unroll
      for (int j = 0; j < 8; ++j)
        bW[j] = (_Float16)Wout[(kk * 32 + g * 8 + j) * 32 + nt * 16 + c16];
      acc = __builtin_amdgcn_mfma_f32_16x16x32_f16(aY, bW, acc, 0, 0, 0);
    }
#pragma unroll
    for (int r = 0; r < 4; ++r) {
      int l = mt * 16 + 4 * g + r;
      int dm = nt * 16 + c16;
      size_t gi = ubase + (size_t)(l0 + l) * DM + dm;
      ym[gi] = __float2half(acc[r] + skipv * __half2float(u[gi]));
    }
  }
}

// ---------------- K5: regroup + LN2 + proj(256x256) + bias + transpose ----------------
__global__ __launch_bounds__(256) void k5_ln_proj(const __half* __restrict__ ym,
                                                  const float* __restrict__ lnw,
                                                  const float* __restrict__ lnb,
                                                  const float* __restrict__ pw,
                                                  const float* __restrict__ pb,
                                                  float* __restrict__ outp) {
  __shared__ float yf[8448];  // LN phase: [32][257]; epilogue: res [256][33]
  __shared__ float mu[32], rs[32], wv[256], bv[256];
  const int b = blockIdx.y, l0 = blockIdx.x * 32, t = threadIdx.x;
  wv[t] = lnw[t];
  bv[t] = lnb[t];
  for (int sp = 0; sp < 8; ++sp) {
#pragma unroll
    for (int i = 0; i < 4; ++i) {
      int idx = i * 256 + t;
      int ll = idx >> 5, dm = idx & 31;
      yf[ll * 257 + sp * 32 + dm] =
          __half2float(ym[(((size_t)(sp * B0N + b)) * LSEQ + l0 + ll) * DM + dm]);
    }
  }
  __syncthreads();
  if (t < 32) {
    float s = 0.f, s2 = 0.f;
    for (int ch = 0; ch < 256; ++ch) {
      float v = yf[t * 257 + ch];
      s += v; s2 += v * v;
    }
    float m = s * (1.f / 256.f);
    mu[t] = m;
    rs[t] = rsqrtf(s2 * (1.f / 256.f) - m * m + 1e-5f);
  }
  __syncthreads();
#pragma unroll 8
  for (int i = 0; i < 32; ++i) {
    int idx = i * 256 + t;
    int ll = idx >> 8, ch = idx & 255;
    yf[ll * 257 + ch] = (yf[ll * 257 + ch] - mu[ll]) * rs[ll] * wv[ch] + bv[ch];
  }
  __syncthreads();
  const int llg = t >> 5, og = t & 31;
  float acc[4][8];
#pragma unroll
  for (int k = 0; k < 4; ++k)
#pragma unroll
    for (int j = 0; j < 8; ++j) acc[k][j] = 0.f;
  for (int ch = 0; ch < 256; ++ch) {
    const float4 w0 = *(const float4*)(pw + (size_t)ch * 256 + og * 8);
    const float4 w1 = *(const float4*)(pw + (size_t)ch * 256 + og * 8 + 4);
#pragma unroll
    for (int k = 0; k < 4; ++k) {
      float y = yf[(llg * 4 + k) * 257 + ch];
      acc[k][0] += y * w0.x; acc[k][1] += y * w0.y; acc[k][2] += y * w0.z; acc[k][3] += y * w0.w;
      acc[k][4] += y * w1.x; acc[k][5] += y * w1.y; acc[k][6] += y * w1.z; acc[k][7] += y * w1.w;
    }
  }
  __syncthreads();  // all yf reads done before overlay
  float* res = yf;  // [256][33]
#pragma unroll
  for (int j = 0; j < 8; ++j) {
    float bias = pb[og * 8 + j];
#pragma unroll
    for (int k = 0; k < 4; ++k)
      res[(og * 8 + j) * 33 + llg * 4 + k] = acc[k][j] + bias;
  }
  __syncthreads();
  for (int idx = t; idx < 8192; idx += 256) {
    int o = idx >> 5, l = idx & 31;
    outp[((size_t)(b * 256 + o)) * LSEQ + l0 + l] = res[o * 33 + l];
  }
}

extern "C" void kernel_launch(void* const* d_in, const int* in_sizes, int n_in,
                              void* d_out, int out_size, void* d_ws, size_t ws_size,
                              hipStream_t stream) {
  (void)in_sizes; (void)n_in; (void)out_size;
  const float* x     = (const float*)d_in[0];
  const float* lnw   = (const float*)d_in[1];
  const float* lnb   = (const float*)d_in[2];
  const float* skip  = (const float*)d_in[3];
  const float* pw    = (const float*)d_in[4];
  const float* pb    = (const float*)d_in[5];
  const float* Win   = (const float*)d_in[6];
  const float* convw = (const float*)d_in[7];
  const float* convb = (const float*)d_in[8];
  const float* dtb   = (const float*)d_in[9];
  const float* Alog  = (const float*)d_in[10];
  const float* Dp    = (const float*)d_in[11];
  const float* rmsw  = (const float*)d_in[12];
  const float* Wout  = (const float*)d_in[13];
  float* outp = (float*)d_out;

  // workspace layout (fp16 tensors): total 227,082,240 B (ws cap proven < 491 MB in R1)
  const size_t NEED = 227082240ull;
  if (ws_size < NEED) return;
  char* ws = (char*)d_ws;
  __half* u    = (__half*)ws;                    //  37,748,736 B
  __half* S    = (__half*)(ws + 37748736);       // 150,994,944 B
  float*  cdec = (float*)(ws + 188743680);       //     589,824 B
  __half* ym   = (__half*)(ws + 189333504);      //  37,748,736 B

  k1_ln_split<<<dim3(288, 8), 256, 0, stream>>>(x, lnw, lnb, u);
  k2_states<<<dim3(288, 64), 256, 0, stream>>>(u, Win, convw, convb, dtb, Alog, S, cdec);
  k3_scan<<<dim3(512), 512, 0, stream>>>(S, cdec);
  k4_out<<<dim3(288, 64), 256, 0, stream>>>(u, Win, convw, convb, dtb, Alog, Dp, rmsw,
                                            Wout, skip, S, ym);
  k5_ln_proj<<<dim3(288, 8), 256, 0, stream>>>(ym, lnw, lnb, pw, pb, outp);
}

// Round 5
// 721.975 us; speedup vs baseline: 3.0291x; 1.5833x over previous
//
#include <hip/hip_runtime.h>
#include <hip/hip_fp16.h>
#include <math.h>

typedef unsigned short u16;
typedef unsigned int u32;
typedef _Float16 half2_t __attribute__((ext_vector_type(2)));
typedef _Float16 f16x8 __attribute__((ext_vector_type(8)));
typedef float f32x4 __attribute__((ext_vector_type(4)));

#define B0N 8
#define LSEQ 9216
#define NSEQ 64
#define NCHUNK 288
#define DM 32
#define DPROJ 264
#define CONVCH 192
#define XC4 208   // k4 xc row stride (fp16, 416B rows -> 16B-aligned for ds_read_b128)
#define URH 40    // ur row stride (fp16, 80B rows -> 16B-aligned, 2-way banks)
#define CHH 204   // k4 CH row stride (fp16)
#define ZBS 66    // k4 zbuf row stride (fp16)
#define CH2S 129  // k2 CH row stride (f32)
#define TTS 40    // k2 transposed xs/B/A row stride (fp16, 80B rows)
#define GS 36     // k4 G row stride (f32, 144B rows -> 16B-aligned)

#ifndef __has_builtin
#define __has_builtin(x) 0
#endif

__device__ __forceinline__ float silu_(float v) { return v / (1.f + __expf(-v)); }

// ---------------- K1: LayerNorm(256) + split -> u (64,9216,32) fp16 ----------------
__global__ __launch_bounds__(256) void k1_ln_split(const float* __restrict__ x,
                                                   const float* __restrict__ lnw,
                                                   const float* __restrict__ lnb,
                                                   __half* __restrict__ u) {
  __shared__ float tile[256 * 33];  // [c][ll]
  __shared__ float mu[32], rs[32], wv[256], bv[256];
  const int b = blockIdx.y, l0 = blockIdx.x * 32, t = threadIdx.x;
  wv[t] = lnw[t];
  bv[t] = lnb[t];
#pragma unroll 4
  for (int i = 0; i < 32; ++i) {
    int c = i * 8 + (t >> 5), ll = t & 31;
    tile[c * 33 + ll] = x[((size_t)b * 256 + c) * LSEQ + l0 + ll];
  }
  __syncthreads();
  if (t < 32) {
    float s = 0.f, s2 = 0.f;
    for (int c = 0; c < 256; ++c) {
      float v = tile[c * 33 + t];
      s += v; s2 += v * v;
    }
    float m = s * (1.f / 256.f);
    mu[t] = m;
    rs[t] = rsqrtf(s2 * (1.f / 256.f) - m * m + 1e-5f);
  }
  __syncthreads();
#pragma unroll 4
  for (int i = 0; i < 32; ++i) {
    int sp = i >> 2, sub = i & 3;
    int ll = sub * 8 + (t >> 5), dm = t & 31;
    int c = sp * 32 + dm;
    float v = (tile[c * 33 + ll] - mu[ll]) * rs[ll] * wv[c] + bv[c];
    u[(((size_t)(sp * B0N + b)) * LSEQ + l0 + ll) * DM + dm] = __float2half(v);
  }
}

// ---------------- K2: in-proj + conv + dt + per-chunk states (MFMA) ----------------
// Only channels 0..127 (xs + B) are needed here; C (128..191) is consumed only by k4.
__global__ __launch_bounds__(256, 2) void k2_states(
    const __half* __restrict__ u, const float* __restrict__ Win,
    const float* __restrict__ convw, const float* __restrict__ convb,
    const float* __restrict__ dtbias, const float* __restrict__ Alog,
    __half* __restrict__ S, float* __restrict__ cdec) {
  __shared__ __align__(16) _Float16 ur_h[48 * URH];  // 3840 B (rows 34..47 zero)
  __shared__ __align__(16) float CH2[34 * CH2S];     // 17544 B; overlay after conv:
                                                     //   Ah fp16 [64][40]  @byte 0    (5120 B)
                                                     //   Sout fp16 [64][72] @byte 5120 (9216 B)
  __shared__ __align__(16) _Float16 xst[64 * TTS];   // 5120 B  xs transposed [hp][l]
  __shared__ __align__(16) _Float16 Bt[64 * TTS];    // 5120 B  B transposed [n][l]
  __shared__ __align__(16) float dtraw[256], dtv[256], acs[256], wv2[256];
  const int c = blockIdx.x, sq = blockIdx.y, t = threadIdx.x;
  const int l0 = c * 32;
  const int lane = t & 63, wvi = t >> 6, g = lane >> 4, c16 = lane & 15;
  const size_t ubase = (size_t)sq * (LSEQ * DM);
  const f32x4 zero4 = {0.f, 0.f, 0.f, 0.f};

  // ---- P0: stage ur (fp16); load Win B-frags (cols 64..191 -> channels 0..127) ----
  for (int idx = t; idx < 48 * 32; idx += 256) {
    int r = idx >> 5, dm = idx & 31;
    int l = l0 - 2 + r;
    _Float16 v = (_Float16)0.f;
    if (r < 34 && l >= 0) v = ((const _Float16*)u)[ubase + (size_t)l * DM + dm];
    ur_h[r * URH + dm] = v;
  }
  f16x8 bfr[2];  // N-tiles nt = wvi, wvi+4
#pragma unroll
  for (int i = 0; i < 2; ++i) {
    int col = 64 + (wvi + i * 4) * 16 + c16;
#pragma unroll
    for (int j = 0; j < 8; ++j) bfr[i][j] = (_Float16)Win[(g * 8 + j) * DPROJ + col];
  }
  __syncthreads();

  // ---- P1: MFMA inproj -> CH2 (34 rows x 128 channels) ----
  {
    f16x8 am[3];
#pragma unroll
    for (int mt = 0; mt < 3; ++mt)
      am[mt] = *(const f16x8*)&ur_h[(mt * 16 + c16) * URH + g * 8];
#pragma unroll
    for (int i = 0; i < 2; ++i) {
      int colc = (wvi + i * 4) * 16 + c16;
#pragma unroll
      for (int mt = 0; mt < 3; ++mt) {
        f32x4 acc = __builtin_amdgcn_mfma_f32_16x16x32_f16(am[mt], bfr[i], zero4, 0, 0, 0);
#pragma unroll
        for (int r = 0; r < 4; ++r) {
          int R = mt * 16 + 4 * g + r;
          if (R < 34) CH2[R * CH2S + colc] = acc[r];
        }
      }
    }
  }
  __syncthreads();

  // ---- P2: conv+silu -> xst/Bt (transposed); dtraw via f32 scalar dot ----
  {
    const int ch0 = t & 63, lb = t >> 6;
    float cw[2][3], cb[2];
#pragma unroll
    for (int cr = 0; cr < 2; ++cr) {
      int ch = ch0 + cr * 64;
      cw[cr][0] = convw[ch * 3 + 0];
      cw[cr][1] = convw[ch * 3 + 1];
      cw[cr][2] = convw[ch * 3 + 2];
      cb[cr] = convb[ch];
    }
#pragma unroll
    for (int lr = 0; lr < 8; ++lr) {
      int l = lb + lr * 4;
#pragma unroll
      for (int cr = 0; cr < 2; ++cr) {
        int ch = ch0 + cr * 64;
        float v = CH2[l * CH2S + ch] * cw[cr][0] + CH2[(l + 1) * CH2S + ch] * cw[cr][1] +
                  CH2[(l + 2) * CH2S + ch] * cw[cr][2] + cb[cr];
        _Float16 sv = (_Float16)silu_(v);
        if (cr == 0) xst[ch * TTS + l] = sv;
        else Bt[(ch - 64) * TTS + l] = sv;
      }
    }
    int l = t >> 3, h = t & 7;
    float raw = 0.f;
#pragma unroll
    for (int dm = 0; dm < 32; ++dm)
      raw += (float)ur_h[(l + 2) * URH + dm] * Win[dm * DPROJ + 256 + h];
    dtraw[l * 8 + h] = raw;
  }
  __syncthreads();

  // ---- P3: dt softplus + prefix scan (parallel; 32-lane Kogge-Stone) + cdec ----
  {
    const int l = t & 31, h = t >> 5;
    float raw = dtraw[l * 8 + h] + dtbias[h];
    float dt = (raw > 20.f) ? raw : log1pf(__expf(raw));
    float x = dt;
#pragma unroll
    for (int d = 1; d < 32; d <<= 1) {
      float y = __shfl_up(x, d, 32);
      if (l >= d) x += y;
    }
    const float A = -__expf(Alog[h]);
    dtv[t] = dt;
    acs[t] = A * x;
    if (l == 31) cdec[(sq * NCHUNK + c) * 8 + h] = __expf(A * x);
  }
  __syncthreads();

  // ---- P4: wv2; build A[hp][l] = wv2[h][l]*xs[l][hp] (fp16, CH2 overlay) ----
  _Float16* Ah = (_Float16*)CH2;
  {
    int h = t >> 5;
    wv2[t] = __expf(acs[h * 32 + 31] - acs[t]) * dtv[t];
  }
  __syncthreads();
  {
    const int hp = t >> 2, lb2 = (t & 3) * 8;
    const float* w = &wv2[(hp >> 3) * 32 + lb2];
    const _Float16* xr = &xst[hp * TTS + lb2];
    _Float16* ar = &Ah[hp * TTS + lb2];
#pragma unroll
    for (int i = 0; i < 8; ++i) ar[i] = (_Float16)((float)xr[i] * w[i]);
  }
  __syncthreads();

  // ---- P5: states MFMA S[hp][n] = A·B -> Sout, then coalesced global store ----
  __half* Sout = (__half*)((char*)CH2 + 5120);  // [64][72] fp16
  {
    const int mt = wvi;
    f16x8 aS = *(const f16x8*)&Ah[(mt * 16 + c16) * TTS + g * 8];
#pragma unroll
    for (int nt = 0; nt < 4; ++nt) {
      f16x8 bS = *(const f16x8*)&Bt[(nt * 16 + c16) * TTS + g * 8];
      f32x4 acc = __builtin_amdgcn_mfma_f32_16x16x32_f16(aS, bS, zero4, 0, 0, 0);
#pragma unroll
      for (int r = 0; r < 4; ++r)
        Sout[(mt * 16 + 4 * g + r) * 72 + nt * 16 + c16] = __float2half(acc[r]);
    }
  }
  __syncthreads();
  const size_t sbase = (size_t)(sq * NCHUNK + c) * 4096;
#pragma unroll
  for (int i = 0; i < 2; ++i) {
    int idx = i * 256 + t;
    int hp = idx >> 3, part = idx & 7;
    *(uint4*)(S + sbase + hp * 64 + part * 8) = *(const uint4*)&Sout[hp * 72 + part * 8];
  }
}

// ---------------- K3: in-place exclusive scan over chunks ----------------
__global__ __launch_bounds__(512) void k3_scan(__half* __restrict__ S,
                                               const float* __restrict__ cdec) {
  const int sq = blockIdx.x >> 3, h = blockIdx.x & 7, t = threadIdx.x;
  float carry = 0.f;
  for (int c = 0; c < NCHUNK; ++c) {
    size_t idx = (size_t)(sq * NCHUNK + c) * 4096 + h * 512 + t;
    float s = __half2float(S[idx]);
    S[idx] = __float2half(carry);
    carry = carry * cdec[(sq * NCHUNK + c) * 8 + h] + s;
  }
}

// ---------------- K4: output pass — MFMA for inproj/z/G/Yd/Yo/Wout ----------------
// MFMA 16x16x32 f16 conventions (gfx950), verified R2:
//   A frag: lane holds A[row = lane&15][k = (lane>>4)*8 + j], j=0..7
//   B frag: lane holds B[k = (lane>>4)*8 + j][col = lane&15]
//   D frag: lane reg r holds D[row = 4*(lane>>4)+r][col = lane&15]
__global__ __launch_bounds__(256, 4) void k4_out(
    const __half* __restrict__ u, const float* __restrict__ Win,
    const float* __restrict__ convw, const float* __restrict__ convb,
    const float* __restrict__ dtbias, const float* __restrict__ Alog,
    const float* __restrict__ Dp, const float* __restrict__ rmsw,
    const float* __restrict__ Wout, const float* __restrict__ skip,
    const __half* __restrict__ S, __half* __restrict__ ym) {
  __shared__ __align__(16) _Float16 ur_h[48 * URH];   // 3840 B; overlays scl f32[32] after P2
  __shared__ __align__(16) _Float16 CHh[34 * CHH];    // 13872 B; overlay after conv:
                                                      //   pv fp16 [64][72] @byte 0    (9216 B)
                                                      //   G  f32  [32][36] @byte 9216 (4608 B) -> RMS partials
  __shared__ __align__(16) __half xch[32 * XC4];      // 13312 B; cols 0..63 xs, 64..127 B->ybuf, 128..191 C
  __shared__ __align__(16) float dtraw[256];          // dtraw [l][h]; later eac[h*32+l]
  __shared__ __align__(16) float dtv[256], acs[256];
  __shared__ __align__(16) _Float16 zbuf[32 * ZBS];   // 4224 B
  const int c = blockIdx.x, sq = blockIdx.y, t = threadIdx.x;
  const int l0 = c * 32;
  const int lane = t & 63, wvi = t >> 6, g = lane >> 4, c16 = lane & 15;
  const size_t ubase = (size_t)sq * (LSEQ * DM);
  const f32x4 zero4 = {0.f, 0.f, 0.f, 0.f};

  // ---- P0: stage ur (fp16), load B-frags (Win via L2), prefetch S into regs ----
  const size_t sbase = (size_t)(sq * NCHUNK + c) * 4096;
  uint4 sv0, sv1;
  {
    const uint4* sp = (const uint4*)(S + sbase);
    sv0 = sp[t * 2];
    sv1 = sp[t * 2 + 1];
  }
  for (int idx = t; idx < 48 * 32; idx += 256) {
    int r = idx >> 5, dm = idx & 31;
    int l = l0 - 2 + r;
    _Float16 v = (_Float16)0.f;
    if (r < 34 && l >= 0) v = ((const _Float16*)u)[ubase + (size_t)l * DM + dm];
    ur_h[r * URH + dm] = v;
  }
  f16x8 bfr[3];  // inproj N-tiles nt = wvi, wvi+4, wvi+8  (channels nt*16.., Win col 64+..)
#pragma unroll
  for (int i = 0; i < 3; ++i) {
    int col = 64 + (wvi + i * 4) * 16 + c16;
#pragma unroll
    for (int j = 0; j < 8; ++j) bfr[i][j] = (_Float16)Win[(g * 8 + j) * DPROJ + col];
  }
  f16x8 bz;  // z N-tile: cols wvi*16..
  {
    int col = wvi * 16 + c16;
#pragma unroll
    for (int j = 0; j < 8; ++j) bz[j] = (_Float16)Win[(g * 8 + j) * DPROJ + col];
  }
  __syncthreads();

  // ---- P1: MFMA inproj -> CHh (fp16), z -> zbuf ----
  {
    f16x8 am[3];
#pragma unroll
    for (int mt = 0; mt < 3; ++mt)
      am[mt] = *(const f16x8*)&ur_h[(mt * 16 + c16) * URH + g * 8];
#pragma unroll
    for (int i = 0; i < 3; ++i) {
      int colc = (wvi + i * 4) * 16 + c16;
#pragma unroll
      for (int mt = 0; mt < 3; ++mt) {
        f32x4 acc = __builtin_amdgcn_mfma_f32_16x16x32_f16(am[mt], bfr[i], zero4, 0, 0, 0);
#pragma unroll
        for (int r = 0; r < 4; ++r) {
          int R = mt * 16 + 4 * g + r;
          if (R < 34) CHh[R * CHH + colc] = (_Float16)acc[r];
        }
      }
    }
#pragma unroll
    for (int mz = 0; mz < 2; ++mz) {
      f16x8 az = *(const f16x8*)&ur_h[(2 + mz * 16 + c16) * URH + g * 8];
      f32x4 acc = __builtin_amdgcn_mfma_f32_16x16x32_f16(az, bz, zero4, 0, 0, 0);
#pragma unroll
      for (int r = 0; r < 4; ++r) {
        int lY = mz * 16 + 4 * g + r;
        zbuf[lY * ZBS + wvi * 16 + c16] = (_Float16)acc[r];
      }
    }
  }
  __syncthreads();

  // ---- P2: conv+silu -> xch (rolling 3-tap over 8 consecutive rows);
  //          dtraw via f32 scalar dot (precision-sensitive) ----
  {
    const int ch0 = t & 63, lbq = t >> 6;  // rows lbq*8 .. lbq*8+7
#pragma unroll
    for (int cr = 0; cr < 3; ++cr) {
      int ch = ch0 + cr * 64;
      float w0 = convw[ch * 3 + 0], w1 = convw[ch * 3 + 1], w2 = convw[ch * 3 + 2];
      float cb = convb[ch];
      float a = (float)CHh[(lbq * 8 + 0) * CHH + ch];
      float b = (float)CHh[(lbq * 8 + 1) * CHH + ch];
#pragma unroll
      for (int j = 0; j < 8; ++j) {
        float cn = (float)CHh[(lbq * 8 + j + 2) * CHH + ch];
        float v = a * w0 + b * w1 + cn * w2 + cb;
        xch[(lbq * 8 + j) * XC4 + ch] = __float2half(silu_(v));
        a = b; b = cn;
      }
    }
    int l = t >> 3, h = t & 7;
    float raw = 0.f;
#pragma unroll
    for (int dm = 0; dm < 32; ++dm)
      raw += (float)ur_h[(l + 2) * URH + dm] * Win[dm * DPROJ + 256 + h];
    dtraw[l * 8 + h] = raw;
  }
  __syncthreads();

  // ---- P3: pv <- S regs (CHh overlay); dt softplus + parallel prefix scan ----
  {
    char* pvb = (char*)CHh;
    int hp = t >> 2, part = t & 3;
    *(uint4*)(pvb + hp * 144 + part * 32) = sv0;
    *(uint4*)(pvb + hp * 144 + part * 32 + 16) = sv1;
  }
  {
    const int l = t & 31, h = t >> 5;
    float raw = dtraw[l * 8 + h] + dtbias[h];
    float dt = (raw > 20.f) ? raw : log1pf(__expf(raw));
    float x = dt;
#pragma unroll
    for (int d = 1; d < 32; d <<= 1) {
      float y = __shfl_up(x, d, 32);
      if (l >= d) x += y;
    }
    dtv[t] = dt;
    acs[t] = -__expf(Alog[h]) * x;
  }
  __syncthreads();

  // ---- P4: eac table; G = C·B^T via MFMA (stride GS=36, 16B-aligned rows) ----
  float* Gm = (float*)((char*)CHh + 9216);
  {
    float ev = __expf(acs[t]);
    dtraw[t] = ev;  // eac[h*32+l]
    const int mt = wvi >> 1, nt = wvi & 1;
    f32x4 acc = zero4;
#pragma unroll
    for (int kk = 0; kk < 2; ++kk) {
      f16x8 aC = *(const f16x8*)&xch[(mt * 16 + c16) * XC4 + 128 + kk * 32 + g * 8];
      f16x8 bB = *(const f16x8*)&xch[(nt * 16 + c16) * XC4 + 64 + kk * 32 + g * 8];
      acc = __builtin_amdgcn_mfma_f32_16x16x32_f16(aC, bB, acc, 0, 0, 0);
    }
#pragma unroll
    for (int r = 0; r < 4; ++r)
      Gm[(mt * 16 + 4 * g + r) * GS + nt * 16 + c16] = acc[r];
  }
  __syncthreads();

  // ---- P5: Yd via MFMA — build masked M-fragments in registers ----
  // M_h[row][s2] = (s2<=row) ? G[row][s2]*exp(acs_row - acs_s2)*dtv[s2] : 0
  // wave wvi handles heads 2wvi, 2wvi+1; D cols 8..15 are duplicates (discarded)
  {
    const int s2b = g * 8;
    float gv[2][8];
#pragma unroll
    for (int mt = 0; mt < 2; ++mt) {
      const float* gr = &Gm[(mt * 16 + c16) * GS + s2b];
      float4 g0 = *(const float4*)gr;
      float4 g1 = *(const float4*)(gr + 4);
      gv[mt][0] = g0.x; gv[mt][1] = g0.y; gv[mt][2] = g0.z; gv[mt][3] = g0.w;
      gv[mt][4] = g1.x; gv[mt][5] = g1.y; gv[mt][6] = g1.z; gv[mt][7] = g1.w;
    }
#pragma unroll
    for (int hh = 0; hh < 2; ++hh) {
      const int h = 2 * wvi + hh;
      const float* ap = &acs[h * 32 + s2b];
      const float* dp = &dtv[h * 32 + s2b];
      float4 a0 = *(const float4*)ap, a1 = *(const float4*)(ap + 4);
      float4 d0 = *(const float4*)dp, d1 = *(const float4*)(dp + 4);
      const float av[8] = {a0.x, a0.y, a0.z, a0.w, a1.x, a1.y, a1.z, a1.w};
      const float dv[8] = {d0.x, d0.y, d0.z, d0.w, d1.x, d1.y, d1.z, d1.w};
      f16x8 bfr2;
#pragma unroll
      for (int j = 0; j < 8; ++j)
        bfr2[j] = *(const _Float16*)&xch[(s2b + j) * XC4 + h * 8 + (c16 & 7)];
#pragma unroll
      for (int mt = 0; mt < 2; ++mt) {
        const int row = mt * 16 + c16;
        const float arow = acs[h * 32 + row];
        f16x8 afr;
#pragma unroll
        for (int j = 0; j < 8; ++j) {
          float m = gv[mt][j] * __expf(arow - av[j]) * dv[j];
          afr[j] = (_Float16)((s2b + j <= row) ? m : 0.f);
        }
        f32x4 dacc = __builtin_amdgcn_mfma_f32_16x16x32_f16(afr, bfr2, zero4, 0, 0, 0);
        if (c16 < 8) {
#pragma unroll
          for (int r = 0; r < 4; ++r)
            xch[(mt * 16 + 4 * g + r) * XC4 + 64 + h * 8 + c16] = __float2half(dacc[r]);
        }
      }
    }
  }
  __syncthreads();

  // ---- P6: Yo = C·PV^T via MFMA, scaled by eac, accumulated into ybuf ----
  {
    const __half* pvh = (const __half*)CHh;  // [64][72] fp16
#pragma unroll
    for (int mt = 0; mt < 2; ++mt) {
      f32x4 acc = zero4;
#pragma unroll
      for (int kk = 0; kk < 2; ++kk) {
        f16x8 aC = *(const f16x8*)&xch[(mt * 16 + c16) * XC4 + 128 + kk * 32 + g * 8];
        f16x8 bP = *(const f16x8*)&pvh[(wvi * 16 + c16) * 72 + kk * 32 + g * 8];
        acc = __builtin_amdgcn_mfma_f32_16x16x32_f16(aC, bP, acc, 0, 0, 0);
      }
      int hp = wvi * 16 + c16;
#pragma unroll
      for (int r = 0; r < 4; ++r) {
        int l = mt * 16 + 4 * g + r;
        float e = dtraw[(hp >> 3) * 32 + l];
        __half* yb = &xch[l * XC4 + 64 + hp];
        *yb = __float2half(__half2float(*yb) + acc[r] * e);
      }
    }
  }
  __syncthreads();

  // ---- P7: +D*xs, gate with silu(z) from zbuf ----
  {
    const int hp = t & 63;
    const float dcoef = Dp[hp >> 3];
#pragma unroll
    for (int k = 0; k < 8; ++k) {
      int l = (k * 256 + t) >> 6;
      float y = __half2float(xch[l * XC4 + 64 + hp]) + (float)xch[l * XC4 + hp] * dcoef;
      float z = (float)zbuf[l * ZBS + hp];
      y *= z / (1.f + __expf(-z));
      xch[l * XC4 + 64 + hp] = __float2half(y);
    }
  }
  __syncthreads();

  // ---- P8: RMS scale factors (two-stage parallel reduce) ----
  float* rp = Gm;                  // [32][9] partials (G dead after P5)
  float* scl = (float*)ur_h;       // ur dead after P2
  {
    const int l = t & 31, seg = t >> 5;
    float p = 0.f;
#pragma unroll
    for (int k = 0; k < 8; ++k) {
      float v = __half2float(xch[l * XC4 + 64 + seg * 8 + k]);
      p += v * v;
    }
    rp[l * 9 + seg] = p;
  }
  __syncthreads();
  if (t < 32) {
    float s2s = 0.f;
#pragma unroll
    for (int seg = 0; seg < 8; ++seg) s2s += rp[t * 9 + seg];
    scl[t] = rsqrtf(s2s * (1.f / 64.f) + 1e-5f);
  }
  __syncthreads();

  // ---- P9: apply rms * rmsw ----
  for (int idx = t; idx < 2048; idx += 256) {
    int l = idx >> 6, hp = idx & 63;
    xch[l * XC4 + 64 + hp] =
        __float2half(__half2float(xch[l * XC4 + 64 + hp]) * scl[l] * rmsw[hp]);
  }
  __syncthreads();

  // ---- P10: y @ Wout via MFMA + skip, store ym ----
  {
    const float skipv = skip[0];
    const int mt = wvi >> 1, nt = wvi & 1;
    f32x4 acc = zero4;
#pragma unroll
    for (int kk = 0; kk < 2; ++kk) {
      f16x8 aY = *(const f16x8*)&xch[(mt * 16 + c16) * XC4 + 64 + kk * 32 + g * 8];
      f16x8 bW;
#pragma unroll
      for (int j = 0; j < 8; ++j)
        bW[j] = (_Float16)Wout[(kk * 32 + g * 8 + j) * 32 + nt * 16 + c16];
      acc = __builtin_amdgcn_mfma_f32_16x16x32_f16(aY, bW, acc, 0, 0, 0);
    }
#pragma unroll
    for (int r = 0; r < 4; ++r) {
      int l = mt * 16 + 4 * g + r;
      int dm = nt * 16 + c16;
      size_t gi = ubase + (size_t)(l0 + l) * DM + dm;
      ym[gi] = __float2half(acc[r] + skipv * __half2float(u[gi]));
    }
  }
}

// ---------------- K5: regroup + LN2 + proj(256x256) + bias + transpose ----------------
__global__ __launch_bounds__(256) void k5_ln_proj(const __half* __restrict__ ym,
                                                  const float* __restrict__ lnw,
                                                  const float* __restrict__ lnb,
                                                  const float* __restrict__ pw,
                                                  const float* __restrict__ pb,
                                                  float* __restrict__ outp) {
  __shared__ float yf[8448];  // LN phase: [32][257]; epilogue: res [256][33]
  __shared__ float mu[32], rs[32], wv[256], bv[256];
  const int b = blockIdx.y, l0 = blockIdx.x * 32, t = threadIdx.x;
  wv[t] = lnw[t];
  bv[t] = lnb[t];
  for (int sp = 0; sp < 8; ++sp) {
#pragma unroll
    for (int i = 0; i < 4; ++i) {
      int idx = i * 256 + t;
      int ll = idx >> 5, dm = idx & 31;
      yf[ll * 257 + sp * 32 + dm] =
          __half2float(ym[(((size_t)(sp * B0N + b)) * LSEQ + l0 + ll) * DM + dm]);
    }
  }
  __syncthreads();
  if (t < 32) {
    float s = 0.f, s2 = 0.f;
    for (int ch = 0; ch < 256; ++ch) {
      float v = yf[t * 257 + ch];
      s += v; s2 += v * v;
    }
    float m = s * (1.f / 256.f);
    mu[t] = m;
    rs[t] = rsqrtf(s2 * (1.f / 256.f) - m * m + 1e-5f);
  }
  __syncthreads();
#pragma unroll 8
  for (int i = 0; i < 32; ++i) {
    int idx = i * 256 + t;
    int ll = idx >> 8, ch = idx & 255;
    yf[ll * 257 + ch] = (yf[ll * 257 + ch] - mu[ll]) * rs[ll] * wv[ch] + bv[ch];
  }
  __syncthreads();
  const int llg = t >> 5, og = t & 31;
  float acc[4][8];
#pragma unroll
  for (int k = 0; k < 4; ++k)
#pragma unroll
    for (int j = 0; j < 8; ++j) acc[k][j] = 0.f;
  for (int ch = 0; ch < 256; ++ch) {
    const float4 w0 = *(const float4*)(pw + (size_t)ch * 256 + og * 8);
    const float4 w1 = *(const float4*)(pw + (size_t)ch * 256 + og * 8 + 4);
#pragma unroll
    for (int k = 0; k < 4; ++k) {
      float y = yf[(llg * 4 + k) * 257 + ch];
      acc[k][0] += y * w0.x; acc[k][1] += y * w0.y; acc[k][2] += y * w0.z; acc[k][3] += y * w0.w;
      acc[k][4] += y * w1.x; acc[k][5] += y * w1.y; acc[k][6] += y * w1.z; acc[k][7] += y * w1.w;
    }
  }
  __syncthreads();  // all yf reads done before overlay
  float* res = yf;  // [256][33]
#pragma unroll
  for (int j = 0; j < 8; ++j) {
    float bias = pb[og * 8 + j];
#pragma unroll
    for (int k = 0; k < 4; ++k)
      res[(og * 8 + j) * 33 + llg * 4 + k] = acc[k][j] + bias;
  }
  __syncthreads();
  for (int idx = t; idx < 8192; idx += 256) {
    int o = idx >> 5, l = idx & 31;
    outp[((size_t)(b * 256 + o)) * LSEQ + l0 + l] = res[o * 33 + l];
  }
}

extern "C" void kernel_launch(void* const* d_in, const int* in_sizes, int n_in,
                              void* d_out, int out_size, void* d_ws, size_t ws_size,
                              hipStream_t stream) {
  (void)in_sizes; (void)n_in; (void)out_size;
  const float* x     = (const float*)d_in[0];
  const float* lnw   = (const float*)d_in[1];
  const float* lnb   = (const float*)d_in[2];
  const float* skip  = (const float*)d_in[3];
  const float* pw    = (const float*)d_in[4];
  const float* pb    = (const float*)d_in[5];
  const float* Win   = (const float*)d_in[6];
  const float* convw = (const float*)d_in[7];
  const float* convb = (const float*)d_in[8];
  const float* dtb   = (const float*)d_in[9];
  const float* Alog  = (const float*)d_in[10];
  const float* Dp    = (const float*)d_in[11];
  const float* rmsw  = (const float*)d_in[12];
  const float* Wout  = (const float*)d_in[13];
  float* outp = (float*)d_out;

  // workspace layout (fp16 tensors): total 227,082,240 B (ws cap proven < 491 MB in R1)
  const size_t NEED = 227082240ull;
  if (ws_size < NEED) return;
  char* ws = (char*)d_ws;
  __half* u    = (__half*)ws;                    //  37,748,736 B
  __half* S    = (__half*)(ws + 37748736);       // 150,994,944 B
  float*  cdec = (float*)(ws + 188743680);       //     589,824 B
  __half* ym   = (__half*)(ws + 189333504);      //  37,748,736 B

  k1_ln_split<<<dim3(288, 8), 256, 0, stream>>>(x, lnw, lnb, u);
  k2_states<<<dim3(288, 64), 256, 0, stream>>>(u, Win, convw, convb, dtb, Alog, S, cdec);
  k3_scan<<<dim3(512), 512, 0, stream>>>(S, cdec);
  k4_out<<<dim3(288, 64), 256, 0, stream>>>(u, Win, convw, convb, dtb, Alog, Dp, rmsw,
                                            Wout, skip, S, ym);
  k5_ln_proj<<<dim3(288, 8), 256, 0, stream>>>(ym, lnw, lnb, pw, pb, outp);
}

// Round 6
// 636.470 us; speedup vs baseline: 3.4361x; 1.1343x over previous
//
#include <hip/hip_runtime.h>
#include <hip/hip_fp16.h>
#include <math.h>

typedef unsigned short u16;
typedef unsigned int u32;
typedef _Float16 half2_t __attribute__((ext_vector_type(2)));
typedef _Float16 f16x8 __attribute__((ext_vector_type(8)));
typedef float f32x4 __attribute__((ext_vector_type(4)));

#define B0N 8
#define LSEQ 9216
#define NSEQ 64
#define NCHUNK 288
#define DM 32
#define DPROJ 264
#define CONVCH 192
#define XC4 208   // k4 xc row stride (fp16, 416B rows -> 16B-aligned for ds_read_b128)
#define URH 40    // ur row stride (fp16, 80B rows -> 16B-aligned, 2-way banks)
#define CHH 204   // k4 CH row stride (fp16)
#define ZBS 66    // k4 zbuf row stride (fp16)
#define CH2S 129  // k2 CH row stride (f32)
#define TTS 40    // k2 transposed xs/B/A row stride (fp16, 80B rows)
#define GS 36     // k4 G row stride (f32, 144B rows -> 16B-aligned)
#define YH5 264   // k5 yh row stride (fp16, 528B rows -> 16B-aligned)

#ifndef __has_builtin
#define __has_builtin(x) 0
#endif

__device__ __forceinline__ float silu_(float v) { return v / (1.f + __expf(-v)); }

// ---------------- K1: LayerNorm(256) + split -> u (64,9216,32) fp16 ----------------
__global__ __launch_bounds__(256) void k1_ln_split(const float* __restrict__ x,
                                                   const float* __restrict__ lnw,
                                                   const float* __restrict__ lnb,
                                                   __half* __restrict__ u) {
  __shared__ float tile[256 * 33];  // [c][ll]
  __shared__ float mu[32], rs[32], wv[256], bv[256];
  __shared__ float ps[32 * 9], ps2[32 * 9];
  const int b = blockIdx.y, l0 = blockIdx.x * 32, t = threadIdx.x;
  wv[t] = lnw[t];
  bv[t] = lnb[t];
#pragma unroll 4
  for (int i = 0; i < 32; ++i) {
    int c = i * 8 + (t >> 5), ll = t & 31;
    tile[c * 33 + ll] = x[((size_t)b * 256 + c) * LSEQ + l0 + ll];
  }
  __syncthreads();
  {
    const int ll = t & 31, seg = t >> 5;
    float s = 0.f, s2 = 0.f;
#pragma unroll 8
    for (int i = 0; i < 32; ++i) {
      float v = tile[(seg * 32 + i) * 33 + ll];
      s += v; s2 += v * v;
    }
    ps[ll * 9 + seg] = s;
    ps2[ll * 9 + seg] = s2;
  }
  __syncthreads();
  if (t < 32) {
    float s = 0.f, s2 = 0.f;
#pragma unroll
    for (int seg = 0; seg < 8; ++seg) { s += ps[t * 9 + seg]; s2 += ps2[t * 9 + seg]; }
    float m = s * (1.f / 256.f);
    mu[t] = m;
    rs[t] = rsqrtf(s2 * (1.f / 256.f) - m * m + 1e-5f);
  }
  __syncthreads();
#pragma unroll 4
  for (int i = 0; i < 32; ++i) {
    int sp = i >> 2, sub = i & 3;
    int ll = sub * 8 + (t >> 5), dm = t & 31;
    int c = sp * 32 + dm;
    float v = (tile[c * 33 + ll] - mu[ll]) * rs[ll] * wv[c] + bv[c];
    u[(((size_t)(sp * B0N + b)) * LSEQ + l0 + ll) * DM + dm] = __float2half(v);
  }
}

// ---------------- K2: in-proj + conv + dt + per-chunk states (MFMA) ----------------
// Only channels 0..127 (xs + B) are needed here; C (128..191) is consumed only by k4.
__global__ __launch_bounds__(256, 2) void k2_states(
    const __half* __restrict__ u, const float* __restrict__ Win,
    const float* __restrict__ convw, const float* __restrict__ convb,
    const float* __restrict__ dtbias, const float* __restrict__ Alog,
    __half* __restrict__ S, float* __restrict__ cdec) {
  __shared__ __align__(16) _Float16 ur_h[48 * URH];  // 3840 B (rows 34..47 zero)
  __shared__ __align__(16) float CH2[34 * CH2S];     // 17544 B; overlay after conv:
                                                     //   Ah fp16 [64][40]  @byte 0    (5120 B)
                                                     //   Sout fp16 [64][72] @byte 5120 (9216 B)
  __shared__ __align__(16) _Float16 xst[64 * TTS];   // 5120 B  xs transposed [hp][l]
  __shared__ __align__(16) _Float16 Bt[64 * TTS];    // 5120 B  B transposed [n][l]
  __shared__ __align__(16) float dtraw[256], dtv[256], acs[256], wv2[256];
  const int c = blockIdx.x, sq = blockIdx.y, t = threadIdx.x;
  const int l0 = c * 32;
  const int lane = t & 63, wvi = t >> 6, g = lane >> 4, c16 = lane & 15;
  const size_t ubase = (size_t)sq * (LSEQ * DM);
  const f32x4 zero4 = {0.f, 0.f, 0.f, 0.f};

  // ---- P0: stage ur (fp16); load Win B-frags (cols 64..191 -> channels 0..127) ----
  for (int idx = t; idx < 48 * 32; idx += 256) {
    int r = idx >> 5, dm = idx & 31;
    int l = l0 - 2 + r;
    _Float16 v = (_Float16)0.f;
    if (r < 34 && l >= 0) v = ((const _Float16*)u)[ubase + (size_t)l * DM + dm];
    ur_h[r * URH + dm] = v;
  }
  f16x8 bfr[2];  // N-tiles nt = wvi, wvi+4
#pragma unroll
  for (int i = 0; i < 2; ++i) {
    int col = 64 + (wvi + i * 4) * 16 + c16;
#pragma unroll
    for (int j = 0; j < 8; ++j) bfr[i][j] = (_Float16)Win[(g * 8 + j) * DPROJ + col];
  }
  __syncthreads();

  // ---- P1: MFMA inproj -> CH2 (34 rows x 128 channels) ----
  {
    f16x8 am[3];
#pragma unroll
    for (int mt = 0; mt < 3; ++mt)
      am[mt] = *(const f16x8*)&ur_h[(mt * 16 + c16) * URH + g * 8];
#pragma unroll
    for (int i = 0; i < 2; ++i) {
      int colc = (wvi + i * 4) * 16 + c16;
#pragma unroll
      for (int mt = 0; mt < 3; ++mt) {
        f32x4 acc = __builtin_amdgcn_mfma_f32_16x16x32_f16(am[mt], bfr[i], zero4, 0, 0, 0);
#pragma unroll
        for (int r = 0; r < 4; ++r) {
          int R = mt * 16 + 4 * g + r;
          if (R < 34) CH2[R * CH2S + colc] = acc[r];
        }
      }
    }
  }
  __syncthreads();

  // ---- P2: conv+silu -> xst/Bt (transposed); dtraw via f32 scalar dot ----
  {
    const int ch0 = t & 63, lb = t >> 6;
    float cw[2][3], cb[2];
#pragma unroll
    for (int cr = 0; cr < 2; ++cr) {
      int ch = ch0 + cr * 64;
      cw[cr][0] = convw[ch * 3 + 0];
      cw[cr][1] = convw[ch * 3 + 1];
      cw[cr][2] = convw[ch * 3 + 2];
      cb[cr] = convb[ch];
    }
#pragma unroll
    for (int lr = 0; lr < 8; ++lr) {
      int l = lb + lr * 4;
#pragma unroll
      for (int cr = 0; cr < 2; ++cr) {
        int ch = ch0 + cr * 64;
        float v = CH2[l * CH2S + ch] * cw[cr][0] + CH2[(l + 1) * CH2S + ch] * cw[cr][1] +
                  CH2[(l + 2) * CH2S + ch] * cw[cr][2] + cb[cr];
        _Float16 sv = (_Float16)silu_(v);
        if (cr == 0) xst[ch * TTS + l] = sv;
        else Bt[(ch - 64) * TTS + l] = sv;
      }
    }
    int l = t >> 3, h = t & 7;
    float raw = 0.f;
#pragma unroll
    for (int dm = 0; dm < 32; ++dm)
      raw += (float)ur_h[(l + 2) * URH + dm] * Win[dm * DPROJ + 256 + h];
    dtraw[l * 8 + h] = raw;
  }
  __syncthreads();

  // ---- P3: dt softplus + prefix scan (parallel; 32-lane Kogge-Stone) + cdec ----
  {
    const int l = t & 31, h = t >> 5;
    float raw = dtraw[l * 8 + h] + dtbias[h];
    float dt = (raw > 20.f) ? raw : log1pf(__expf(raw));
    float x = dt;
#pragma unroll
    for (int d = 1; d < 32; d <<= 1) {
      float y = __shfl_up(x, d, 32);
      if (l >= d) x += y;
    }
    const float A = -__expf(Alog[h]);
    dtv[t] = dt;
    acs[t] = A * x;
    if (l == 31) cdec[(sq * NCHUNK + c) * 8 + h] = __expf(A * x);
  }
  __syncthreads();

  // ---- P4: wv2; build A[hp][l] = wv2[h][l]*xs[l][hp] (fp16, CH2 overlay) ----
  _Float16* Ah = (_Float16*)CH2;
  {
    int h = t >> 5;
    wv2[t] = __expf(acs[h * 32 + 31] - acs[t]) * dtv[t];
  }
  __syncthreads();
  {
    const int hp = t >> 2, lb2 = (t & 3) * 8;
    const float* w = &wv2[(hp >> 3) * 32 + lb2];
    const _Float16* xr = &xst[hp * TTS + lb2];
    _Float16* ar = &Ah[hp * TTS + lb2];
#pragma unroll
    for (int i = 0; i < 8; ++i) ar[i] = (_Float16)((float)xr[i] * w[i]);
  }
  __syncthreads();

  // ---- P5: states MFMA S[hp][n] = A·B -> Sout, then coalesced global store ----
  __half* Sout = (__half*)((char*)CH2 + 5120);  // [64][72] fp16
  {
    const int mt = wvi;
    f16x8 aS = *(const f16x8*)&Ah[(mt * 16 + c16) * TTS + g * 8];
#pragma unroll
    for (int nt = 0; nt < 4; ++nt) {
      f16x8 bS = *(const f16x8*)&Bt[(nt * 16 + c16) * TTS + g * 8];
      f32x4 acc = __builtin_amdgcn_mfma_f32_16x16x32_f16(aS, bS, zero4, 0, 0, 0);
#pragma unroll
      for (int r = 0; r < 4; ++r)
        Sout[(mt * 16 + 4 * g + r) * 72 + nt * 16 + c16] = __float2half(acc[r]);
    }
  }
  __syncthreads();
  const size_t sbase = (size_t)(sq * NCHUNK + c) * 4096;
#pragma unroll
  for (int i = 0; i < 2; ++i) {
    int idx = i * 256 + t;
    int hp = idx >> 3, part = idx & 7;
    *(uint4*)(S + sbase + hp * 64 + part * 8) = *(const uint4*)&Sout[hp * 72 + part * 8];
  }
}

// ---------------- K3: in-place exclusive scan over chunks ----------------
__global__ __launch_bounds__(512) void k3_scan(__half* __restrict__ S,
                                               const float* __restrict__ cdec) {
  const int sq = blockIdx.x >> 3, h = blockIdx.x & 7, t = threadIdx.x;
  float carry = 0.f;
  for (int c = 0; c < NCHUNK; ++c) {
    size_t idx = (size_t)(sq * NCHUNK + c) * 4096 + h * 512 + t;
    float s = __half2float(S[idx]);
    S[idx] = __float2half(carry);
    carry = carry * cdec[(sq * NCHUNK + c) * 8 + h] + s;
  }
}

// ---------------- K4: output pass — MFMA for inproj/z/G/Yd/Yo/Wout ----------------
// MFMA 16x16x32 f16 conventions (gfx950), verified R2:
//   A frag: lane holds A[row = lane&15][k = (lane>>4)*8 + j], j=0..7
//   B frag: lane holds B[k = (lane>>4)*8 + j][col = lane&15]
//   D frag: lane reg r holds D[row = 4*(lane>>4)+r][col = lane&15]
__global__ __launch_bounds__(256, 4) void k4_out(
    const __half* __restrict__ u, const float* __restrict__ Win,
    const float* __restrict__ convw, const float* __restrict__ convb,
    const float* __restrict__ dtbias, const float* __restrict__ Alog,
    const float* __restrict__ Dp, const float* __restrict__ rmsw,
    const float* __restrict__ Wout, const float* __restrict__ skip,
    const __half* __restrict__ S, __half* __restrict__ ym) {
  __shared__ __align__(16) _Float16 ur_h[48 * URH];   // 3840 B; overlays scl f32[32] after P2
  __shared__ __align__(16) _Float16 CHh[34 * CHH];    // 13872 B; overlay after conv:
                                                      //   pv fp16 [64][72] @byte 0    (9216 B)
                                                      //   G  f32  [32][36] @byte 9216 (4608 B) -> RMS partials
  __shared__ __align__(16) __half xch[32 * XC4];      // 13312 B; cols 0..63 xs, 64..127 B->ybuf, 128..191 C
  __shared__ __align__(16) float dtraw[256];          // dtraw [l][h]; later eac[h*32+l]
  __shared__ __align__(16) float dtv[256], acs[256];
  __shared__ __align__(16) _Float16 zbuf[32 * ZBS];   // 4224 B
  const int c = blockIdx.x, sq = blockIdx.y, t = threadIdx.x;
  const int l0 = c * 32;
  const int lane = t & 63, wvi = t >> 6, g = lane >> 4, c16 = lane & 15;
  const size_t ubase = (size_t)sq * (LSEQ * DM);
  const f32x4 zero4 = {0.f, 0.f, 0.f, 0.f};

  // ---- P0: stage ur (fp16), load B-frags (Win via L2), prefetch S into regs ----
  const size_t sbase = (size_t)(sq * NCHUNK + c) * 4096;
  uint4 sv0, sv1;
  {
    const uint4* sp = (const uint4*)(S + sbase);
    sv0 = sp[t * 2];
    sv1 = sp[t * 2 + 1];
  }
  for (int idx = t; idx < 48 * 32; idx += 256) {
    int r = idx >> 5, dm = idx & 31;
    int l = l0 - 2 + r;
    _Float16 v = (_Float16)0.f;
    if (r < 34 && l >= 0) v = ((const _Float16*)u)[ubase + (size_t)l * DM + dm];
    ur_h[r * URH + dm] = v;
  }
  f16x8 bfr[3];  // inproj N-tiles nt = wvi, wvi+4, wvi+8  (channels nt*16.., Win col 64+..)
#pragma unroll
  for (int i = 0; i < 3; ++i) {
    int col = 64 + (wvi + i * 4) * 16 + c16;
#pragma unroll
    for (int j = 0; j < 8; ++j) bfr[i][j] = (_Float16)Win[(g * 8 + j) * DPROJ + col];
  }
  f16x8 bz;  // z N-tile: cols wvi*16..
  {
    int col = wvi * 16 + c16;
#pragma unroll
    for (int j = 0; j < 8; ++j) bz[j] = (_Float16)Win[(g * 8 + j) * DPROJ + col];
  }
  __syncthreads();

  // ---- P1: MFMA inproj -> CHh (fp16), z -> zbuf ----
  {
    f16x8 am[3];
#pragma unroll
    for (int mt = 0; mt < 3; ++mt)
      am[mt] = *(const f16x8*)&ur_h[(mt * 16 + c16) * URH + g * 8];
#pragma unroll
    for (int i = 0; i < 3; ++i) {
      int colc = (wvi + i * 4) * 16 + c16;
#pragma unroll
      for (int mt = 0; mt < 3; ++mt) {
        f32x4 acc = __builtin_amdgcn_mfma_f32_16x16x32_f16(am[mt], bfr[i], zero4, 0, 0, 0);
#pragma unroll
        for (int r = 0; r < 4; ++r) {
          int R = mt * 16 + 4 * g + r;
          if (R < 34) CHh[R * CHH + colc] = (_Float16)acc[r];
        }
      }
    }
#pragma unroll
    for (int mz = 0; mz < 2; ++mz) {
      f16x8 az = *(const f16x8*)&ur_h[(2 + mz * 16 + c16) * URH + g * 8];
      f32x4 acc = __builtin_amdgcn_mfma_f32_16x16x32_f16(az, bz, zero4, 0, 0, 0);
#pragma unroll
      for (int r = 0; r < 4; ++r) {
        int lY = mz * 16 + 4 * g + r;
        zbuf[lY * ZBS + wvi * 16 + c16] = (_Float16)acc[r];
      }
    }
  }
  __syncthreads();

  // ---- P2: conv+silu -> xch (rolling 3-tap over 8 consecutive rows);
  //          dtraw via f32 scalar dot (precision-sensitive) ----
  {
    const int ch0 = t & 63, lbq = t >> 6;  // rows lbq*8 .. lbq*8+7
#pragma unroll
    for (int cr = 0; cr < 3; ++cr) {
      int ch = ch0 + cr * 64;
      float w0 = convw[ch * 3 + 0], w1 = convw[ch * 3 + 1], w2 = convw[ch * 3 + 2];
      float cb = convb[ch];
      float a = (float)CHh[(lbq * 8 + 0) * CHH + ch];
      float b = (float)CHh[(lbq * 8 + 1) * CHH + ch];
#pragma unroll
      for (int j = 0; j < 8; ++j) {
        float cn = (float)CHh[(lbq * 8 + j + 2) * CHH + ch];
        float v = a * w0 + b * w1 + cn * w2 + cb;
        xch[(lbq * 8 + j) * XC4 + ch] = __float2half(silu_(v));
        a = b; b = cn;
      }
    }
    int l = t >> 3, h = t & 7;
    float raw = 0.f;
#pragma unroll
    for (int dm = 0; dm < 32; ++dm)
      raw += (float)ur_h[(l + 2) * URH + dm] * Win[dm * DPROJ + 256 + h];
    dtraw[l * 8 + h] = raw;
  }
  __syncthreads();

  // ---- P3: pv <- S regs (CHh overlay); dt softplus + parallel prefix scan ----
  {
    char* pvb = (char*)CHh;
    int hp = t >> 2, part = t & 3;
    *(uint4*)(pvb + hp * 144 + part * 32) = sv0;
    *(uint4*)(pvb + hp * 144 + part * 32 + 16) = sv1;
  }
  {
    const int l = t & 31, h = t >> 5;
    float raw = dtraw[l * 8 + h] + dtbias[h];
    float dt = (raw > 20.f) ? raw : log1pf(__expf(raw));
    float x = dt;
#pragma unroll
    for (int d = 1; d < 32; d <<= 1) {
      float y = __shfl_up(x, d, 32);
      if (l >= d) x += y;
    }
    dtv[t] = dt;
    acs[t] = -__expf(Alog[h]) * x;
  }
  __syncthreads();

  // ---- P4: eac table; G = C·B^T via MFMA (stride GS=36, 16B-aligned rows) ----
  float* Gm = (float*)((char*)CHh + 9216);
  {
    float ev = __expf(acs[t]);
    dtraw[t] = ev;  // eac[h*32+l]
    const int mt = wvi >> 1, nt = wvi & 1;
    f32x4 acc = zero4;
#pragma unroll
    for (int kk = 0; kk < 2; ++kk) {
      f16x8 aC = *(const f16x8*)&xch[(mt * 16 + c16) * XC4 + 128 + kk * 32 + g * 8];
      f16x8 bB = *(const f16x8*)&xch[(nt * 16 + c16) * XC4 + 64 + kk * 32 + g * 8];
      acc = __builtin_amdgcn_mfma_f32_16x16x32_f16(aC, bB, acc, 0, 0, 0);
    }
#pragma unroll
    for (int r = 0; r < 4; ++r)
      Gm[(mt * 16 + 4 * g + r) * GS + nt * 16 + c16] = acc[r];
  }
  __syncthreads();

  // ---- P5: Yd via MFMA — build masked M-fragments in registers ----
  // M_h[row][s2] = (s2<=row) ? G[row][s2]*exp(acs_row - acs_s2)*dtv[s2] : 0
  // wave wvi handles heads 2wvi, 2wvi+1; D cols 8..15 are duplicates (discarded)
  {
    const int s2b = g * 8;
    float gv[2][8];
#pragma unroll
    for (int mt = 0; mt < 2; ++mt) {
      const float* gr = &Gm[(mt * 16 + c16) * GS + s2b];
      float4 g0 = *(const float4*)gr;
      float4 g1 = *(const float4*)(gr + 4);
      gv[mt][0] = g0.x; gv[mt][1] = g0.y; gv[mt][2] = g0.z; gv[mt][3] = g0.w;
      gv[mt][4] = g1.x; gv[mt][5] = g1.y; gv[mt][6] = g1.z; gv[mt][7] = g1.w;
    }
#pragma unroll
    for (int hh = 0; hh < 2; ++hh) {
      const int h = 2 * wvi + hh;
      const float* ap = &acs[h * 32 + s2b];
      const float* dp = &dtv[h * 32 + s2b];
      float4 a0 = *(const float4*)ap, a1 = *(const float4*)(ap + 4);
      float4 d0 = *(const float4*)dp, d1 = *(const float4*)(dp + 4);
      const float av[8] = {a0.x, a0.y, a0.z, a0.w, a1.x, a1.y, a1.z, a1.w};
      const float dv[8] = {d0.x, d0.y, d0.z, d0.w, d1.x, d1.y, d1.z, d1.w};
      f16x8 bfr2;
#pragma unroll
      for (int j = 0; j < 8; ++j)
        bfr2[j] = *(const _Float16*)&xch[(s2b + j) * XC4 + h * 8 + (c16 & 7)];
#pragma unroll
      for (int mt = 0; mt < 2; ++mt) {
        const int row = mt * 16 + c16;
        const float arow = acs[h * 32 + row];
        f16x8 afr;
#pragma unroll
        for (int j = 0; j < 8; ++j) {
          float m = gv[mt][j] * __expf(arow - av[j]) * dv[j];
          afr[j] = (_Float16)((s2b + j <= row) ? m : 0.f);
        }
        f32x4 dacc = __builtin_amdgcn_mfma_f32_16x16x32_f16(afr, bfr2, zero4, 0, 0, 0);
        if (c16 < 8) {
#pragma unroll
          for (int r = 0; r < 4; ++r)
            xch[(mt * 16 + 4 * g + r) * XC4 + 64 + h * 8 + c16] = __float2half(dacc[r]);
        }
      }
    }
  }
  __syncthreads();

  // ---- P6: Yo = C·PV^T via MFMA, scaled by eac, accumulated into ybuf ----
  {
    const __half* pvh = (const __half*)CHh;  // [64][72] fp16
#pragma unroll
    for (int mt = 0; mt < 2; ++mt) {
      f32x4 acc = zero4;
#pragma unroll
      for (int kk = 0; kk < 2; ++kk) {
        f16x8 aC = *(const f16x8*)&xch[(mt * 16 + c16) * XC4 + 128 + kk * 32 + g * 8];
        f16x8 bP = *(const f16x8*)&pvh[(wvi * 16 + c16) * 72 + kk * 32 + g * 8];
        acc = __builtin_amdgcn_mfma_f32_16x16x32_f16(aC, bP, acc, 0, 0, 0);
      }
      int hp = wvi * 16 + c16;
#pragma unroll
      for (int r = 0; r < 4; ++r) {
        int l = mt * 16 + 4 * g + r;
        float e = dtraw[(hp >> 3) * 32 + l];
        __half* yb = &xch[l * XC4 + 64 + hp];
        *yb = __float2half(__half2float(*yb) + acc[r] * e);
      }
    }
  }
  __syncthreads();

  // ---- P7: +D*xs, gate with silu(z) from zbuf ----
  {
    const int hp = t & 63;
    const float dcoef = Dp[hp >> 3];
#pragma unroll
    for (int k = 0; k < 8; ++k) {
      int l = (k * 256 + t) >> 6;
      float y = __half2float(xch[l * XC4 + 64 + hp]) + (float)xch[l * XC4 + hp] * dcoef;
      float z = (float)zbuf[l * ZBS + hp];
      y *= z / (1.f + __expf(-z));
      xch[l * XC4 + 64 + hp] = __float2half(y);
    }
  }
  __syncthreads();

  // ---- P8: RMS scale factors (two-stage parallel reduce) ----
  float* rp = Gm;                  // [32][9] partials (G dead after P5)
  float* scl = (float*)ur_h;       // ur dead after P2
  {
    const int l = t & 31, seg = t >> 5;
    float p = 0.f;
#pragma unroll
    for (int k = 0; k < 8; ++k) {
      float v = __half2float(xch[l * XC4 + 64 + seg * 8 + k]);
      p += v * v;
    }
    rp[l * 9 + seg] = p;
  }
  __syncthreads();
  if (t < 32) {
    float s2s = 0.f;
#pragma unroll
    for (int seg = 0; seg < 8; ++seg) s2s += rp[t * 9 + seg];
    scl[t] = rsqrtf(s2s * (1.f / 64.f) + 1e-5f);
  }
  __syncthreads();

  // ---- P9: apply rms * rmsw ----
  for (int idx = t; idx < 2048; idx += 256) {
    int l = idx >> 6, hp = idx & 63;
    xch[l * XC4 + 64 + hp] =
        __float2half(__half2float(xch[l * XC4 + 64 + hp]) * scl[l] * rmsw[hp]);
  }
  __syncthreads();

  // ---- P10: y @ Wout via MFMA + skip, store ym ----
  {
    const float skipv = skip[0];
    const int mt = wvi >> 1, nt = wvi & 1;
    f32x4 acc = zero4;
#pragma unroll
    for (int kk = 0; kk < 2; ++kk) {
      f16x8 aY = *(const f16x8*)&xch[(mt * 16 + c16) * XC4 + 64 + kk * 32 + g * 8];
      f16x8 bW;
#pragma unroll
      for (int j = 0; j < 8; ++j)
        bW[j] = (_Float16)Wout[(kk * 32 + g * 8 + j) * 32 + nt * 16 + c16];
      acc = __builtin_amdgcn_mfma_f32_16x16x32_f16(aY, bW, acc, 0, 0, 0);
    }
#pragma unroll
    for (int r = 0; r < 4; ++r) {
      int l = mt * 16 + 4 * g + r;
      int dm = nt * 16 + c16;
      size_t gi = ubase + (size_t)(l0 + l) * DM + dm;
      ym[gi] = __float2half(acc[r] + skipv * __half2float(u[gi]));
    }
  }
}

// ---------------- K5: regroup + LN2 + proj(256x256) via MFMA + transpose ----------------
__global__ __launch_bounds__(256, 4) void k5_ln_proj(const __half* __restrict__ ym,
                                                     const float* __restrict__ lnw,
                                                     const float* __restrict__ lnb,
                                                     const float* __restrict__ pw,
                                                     const float* __restrict__ pb,
                                                     float* __restrict__ outp) {
  __shared__ __align__(16) char buf[33792];  // phase A: yh fp16 [32][YH5] (16896 B)
                                             // phase B: res f32 [256][33] (33792 B)
  __shared__ float mu[32], rs[32], wv[256], bv[256];
  __shared__ float ps[32 * 9], ps2[32 * 9];
  _Float16* yh = (_Float16*)buf;
  float* res = (float*)buf;
  const int b = blockIdx.y, l0 = blockIdx.x * 32, t = threadIdx.x;
  const int lane = t & 63, wvi = t >> 6, g = lane >> 4, c16 = lane & 15;
  const f32x4 zero4 = {0.f, 0.f, 0.f, 0.f};
  wv[t] = lnw[t];
  bv[t] = lnb[t];
  // ---- load ym -> yh fp16 [ll][sp*32+dm] (half2 moves) ----
  for (int sp = 0; sp < 8; ++sp) {
#pragma unroll
    for (int i = 0; i < 2; ++i) {
      int idx = i * 256 + t;
      int ll = idx >> 4, dmp = (idx & 15) * 2;
      u32 v = *(const u32*)&ym[(((size_t)(sp * B0N + b)) * LSEQ + l0 + ll) * DM + dmp];
      *(u32*)&yh[ll * YH5 + sp * 32 + dmp] = v;
    }
  }
  __syncthreads();
  // ---- LN stats (two-stage parallel) ----
  {
    const int ll = t & 31, seg = t >> 5;
    float s = 0.f, s2 = 0.f;
#pragma unroll 8
    for (int i = 0; i < 32; ++i) {
      float v = (float)yh[ll * YH5 + seg * 32 + i];
      s += v; s2 += v * v;
    }
    ps[ll * 9 + seg] = s;
    ps2[ll * 9 + seg] = s2;
  }
  __syncthreads();
  if (t < 32) {
    float s = 0.f, s2 = 0.f;
#pragma unroll
    for (int seg = 0; seg < 8; ++seg) { s += ps[t * 9 + seg]; s2 += ps2[t * 9 + seg]; }
    float m = s * (1.f / 256.f);
    mu[t] = m;
    rs[t] = rsqrtf(s2 * (1.f / 256.f) - m * m + 1e-5f);
  }
  __syncthreads();
  // ---- LN apply in place (fp16) ----
#pragma unroll
  for (int i = 0; i < 32; ++i) {
    int idx = i * 256 + t;
    int ll = idx >> 8, ch = idx & 255;
    float v = ((float)yh[ll * YH5 + ch] - mu[ll]) * rs[ll] * wv[ch] + bv[ch];
    yh[ll * YH5 + ch] = (_Float16)v;
  }
  __syncthreads();
  // ---- hoist A-frags to registers (16 x f16x8), then overlay res ----
  f16x8 am[16];
#pragma unroll
  for (int mt = 0; mt < 2; ++mt)
#pragma unroll
    for (int kk = 0; kk < 8; ++kk)
      am[mt * 8 + kk] = *(const f16x8*)&yh[(mt * 16 + c16) * YH5 + kk * 32 + g * 8];
  __syncthreads();  // all yh reads complete; buf becomes res
  // ---- proj GEMM: wave wvi owns n-tiles wvi, wvi+4, wvi+8, wvi+12 ----
#pragma unroll
  for (int ni = 0; ni < 4; ++ni) {
    const int col = (wvi + ni * 4) * 16 + c16;
    f32x4 acc0 = zero4, acc1 = zero4;
#pragma unroll
    for (int kk = 0; kk < 8; ++kk) {
      f16x8 bW;
#pragma unroll
      for (int j = 0; j < 8; ++j)
        bW[j] = (_Float16)pw[(size_t)(kk * 32 + g * 8 + j) * 256 + col];
      acc0 = __builtin_amdgcn_mfma_f32_16x16x32_f16(am[kk], bW, acc0, 0, 0, 0);
      acc1 = __builtin_amdgcn_mfma_f32_16x16x32_f16(am[8 + kk], bW, acc1, 0, 0, 0);
    }
    const float bias = pb[col];
#pragma unroll
    for (int r = 0; r < 4; ++r) {
      res[col * 33 + 4 * g + r] = acc0[r] + bias;
      res[col * 33 + 16 + 4 * g + r] = acc1[r] + bias;
    }
  }
  __syncthreads();
  // ---- store (transpose to NCHW) ----
  for (int idx = t; idx < 8192; idx += 256) {
    int o = idx >> 5, l = idx & 31;
    outp[((size_t)(b * 256 + o)) * LSEQ + l0 + l] = res[o * 33 + l];
  }
}

extern "C" void kernel_launch(void* const* d_in, const int* in_sizes, int n_in,
                              void* d_out, int out_size, void* d_ws, size_t ws_size,
                              hipStream_t stream) {
  (void)in_sizes; (void)n_in; (void)out_size;
  const float* x     = (const float*)d_in[0];
  const float* lnw   = (const float*)d_in[1];
  const float* lnb   = (const float*)d_in[2];
  const float* skip  = (const float*)d_in[3];
  const float* pw    = (const float*)d_in[4];
  const float* pb    = (const float*)d_in[5];
  const float* Win   = (const float*)d_in[6];
  const float* convw = (const float*)d_in[7];
  const float* convb = (const float*)d_in[8];
  const float* dtb   = (const float*)d_in[9];
  const float* Alog  = (const float*)d_in[10];
  const float* Dp    = (const float*)d_in[11];
  const float* rmsw  = (const float*)d_in[12];
  const float* Wout  = (const float*)d_in[13];
  float* outp = (float*)d_out;

  // workspace layout (fp16 tensors): total 227,082,240 B (ws cap proven < 491 MB in R1)
  const size_t NEED = 227082240ull;
  if (ws_size < NEED) return;
  char* ws = (char*)d_ws;
  __half* u    = (__half*)ws;                    //  37,748,736 B
  __half* S    = (__half*)(ws + 37748736);       // 150,994,944 B
  float*  cdec = (float*)(ws + 188743680);       //     589,824 B
  __half* ym   = (__half*)(ws + 189333504);      //  37,748,736 B

  k1_ln_split<<<dim3(288, 8), 256, 0, stream>>>(x, lnw, lnb, u);
  k2_states<<<dim3(288, 64), 256, 0, stream>>>(u, Win, convw, convb, dtb, Alog, S, cdec);
  k3_scan<<<dim3(512), 512, 0, stream>>>(S, cdec);
  k4_out<<<dim3(288, 64), 256, 0, stream>>>(u, Win, convw, convb, dtb, Alog, Dp, rmsw,
                                            Wout, skip, S, ym);
  k5_ln_proj<<<dim3(288, 8), 256, 0, stream>>>(ym, lnw, lnb, pw, pb, outp);
}